// Round 12
// baseline (974.389 us; speedup 1.0000x reference)
//
#include <hip/hip_runtime.h>
#include <hip/hip_bf16.h>
#include <type_traits>

#define NN 50000
#define NP 50048   // NN padded to 64*782
#define EE 800000
#define TT 3
#define ED 64
#define NS 23
#define MD 87
#define HH 200
#define NMOL 2048
#define RD 256

#define SP 216     // LDS hi-plane stride (shorts)
#define NPB2 512   // colstats partial blocks

typedef __attribute__((ext_vector_type(8))) short short8b;
typedef __attribute__((ext_vector_type(4))) short short4b;
typedef __attribute__((ext_vector_type(4))) float f32x4;

// ---- bf16 helpers ----
__device__ __forceinline__ unsigned short f2bf(float f) {
  unsigned u = __float_as_uint(f);
  return (unsigned short)((u + 0x7fffu + ((u >> 16) & 1u)) >> 16);
}
__device__ __forceinline__ float ubf2f(unsigned short h) {
  return __uint_as_float(((unsigned)h) << 16);
}
// interleaved pair in one u32: low16 = hi-bf16, high16 = lo-bf16 (fp32-equivalent)
__device__ __forceinline__ float bfp2f(unsigned p) {
  return __uint_as_float(p << 16) + __uint_as_float(p & 0xffff0000u);
}
__device__ __forceinline__ unsigned packsplit(float v) {
  unsigned short h = f2bf(v);
  unsigned short l = f2bf(v - ubf2f(h));
  return (unsigned)h | ((unsigned)l << 16);
}

// ---------------- weight prep: fp32 [T][K][N] -> bf16 hi/lo planes [T][Npad][Kpad] ----
struct WD { const float* src; short* dh; short* dl; int K, N, Kpad, Npad, T; };
struct WDs { WD d[7]; };

__global__ __launch_bounds__(256) void wprep_kernel(WDs W) {
  WD w = W.d[blockIdx.y];
  int per = w.Npad * w.Kpad;
  int total = w.T * per;
  for (int idx = blockIdx.x * 256 + threadIdx.x; idx < total; idx += gridDim.x * 256) {
    int t = idx / per;
    int r = idx - t * per;
    int n = r / w.Kpad;
    int k = r - n * w.Kpad;
    float v = 0.f;
    if (k < w.K && n < w.N) v = w.src[((size_t)t * w.K + k) * w.N + n];
    unsigned short h = f2bf(v);
    unsigned short l = f2bf(v - ubf2f(h));
    w.dh[idx] = (short)h;
    w.dl[idx] = (short)l;
  }
}

// ---------------- embedding -> x slice 0 (pair + hi plane) ----------------
__global__ __launch_bounds__(256) void emb_kernel(const int* __restrict__ z,
                                                  const float* __restrict__ emb,
                                                  unsigned* __restrict__ xp,
                                                  short* __restrict__ xq) {
  int idx = blockIdx.x * 256 + threadIdx.x;
  if (idx >= NN * ED) return;
  int i = idx >> 6, d = idx & 63;
  unsigned pk = packsplit(emb[z[i] * ED + d]);
  xp[(size_t)i * RD + d] = pk;
  xq[(size_t)i * RD + d] = (short)(pk & 0xffffu);
}

// ---------------- CSR build ----------------
__global__ __launch_bounds__(256) void hist_kernel(const int* __restrict__ src,
                                                   int* __restrict__ deg) {
  int e = blockIdx.x * 256 + threadIdx.x;
  if (e < EE) atomicAdd(&deg[src[e]], 1);
}

__global__ __launch_bounds__(1024) void scan_kernel(const int* __restrict__ deg,
                                                    int* __restrict__ offs,
                                                    int* __restrict__ cursor) {
  __shared__ int sh[1024];
  int tid = threadIdx.x;
  const int CH = (NN + 1023) / 1024;
  int s0 = tid * CH, s1 = s0 + CH;
  if (s1 > NN) s1 = NN;
  int sum = 0;
  for (int i = s0; i < s1; i++) sum += deg[i];
  sh[tid] = sum;
  __syncthreads();
  for (int off = 1; off < 1024; off <<= 1) {
    int t = (tid >= off) ? sh[tid - off] : 0;
    __syncthreads();
    sh[tid] += t;
    __syncthreads();
  }
  int base = sh[tid] - sum;
  for (int i = s0; i < s1; i++) {
    offs[i] = base;
    cursor[i] = base;
    base += deg[i];
  }
  if (tid == 1023) offs[NN] = sh[1023];
}

__global__ __launch_bounds__(256) void scatter_kernel(const int* __restrict__ src,
                                                      const int* __restrict__ snk,
                                                      const float* __restrict__ dist,
                                                      int* __restrict__ cursor,
                                                      int* __restrict__ ssink,
                                                      float* __restrict__ sdist) {
  int e = blockIdx.x * 256 + threadIdx.x;
  if (e >= EE) return;
  int p = atomicAdd(&cursor[src[e]], 1);
  ssink[p] = snk[e];
  sdist[p] = dist[e];
}

// ---------------- message gather: one wave per node, hi-plane reads ----------
__global__ __launch_bounds__(256) void gather_kernel(const int* __restrict__ offs,
                                                     const int* __restrict__ ssink,
                                                     const float* __restrict__ sdist,
                                                     const short* __restrict__ xq,
                                                     int toff, unsigned* __restrict__ m) {
  int node = blockIdx.x * 4 + (threadIdx.x >> 6);
  int lane = threadIdx.x & 63;
  if (node >= NN) return;
  float shift = (float)(0.8 + 0.1 * (double)lane);
  int e0 = offs[node], e1 = offs[node + 1];
  float ax0 = 0.f, ax1 = 0.f, ar0 = 0.f, ar1 = 0.f;
  int j = e0;
  for (; j + 4 <= e1; j += 4) {
    int s0 = ssink[j], s1 = ssink[j + 1], s2 = ssink[j + 2], s3 = ssink[j + 3];
    float d0 = sdist[j], d1 = sdist[j + 1], d2 = sdist[j + 2], d3 = sdist[j + 3];
    float x0 = ubf2f((unsigned short)xq[(size_t)s0 * RD + toff + lane]);
    float x1 = ubf2f((unsigned short)xq[(size_t)s1 * RD + toff + lane]);
    float x2 = ubf2f((unsigned short)xq[(size_t)s2 * RD + toff + lane]);
    float x3 = ubf2f((unsigned short)xq[(size_t)s3 * RD + toff + lane]);
    ax0 += x0 + x2;
    ax1 += x1 + x3;
    if (lane < NS) {
      float u0 = d0 - shift, u1 = d1 - shift, u2 = d2 - shift, u3 = d3 - shift;
      ar0 += __expf(-u0 * u0) + __expf(-u2 * u2);
      ar1 += __expf(-u1 * u1) + __expf(-u3 * u3);
    }
  }
  for (; j < e1; j++) {
    int s = ssink[j];
    float d = sdist[j];
    ax0 += ubf2f((unsigned short)xq[(size_t)s * RD + toff + lane]);
    if (lane < NS) {
      float u = d - shift;
      ar0 += __expf(-u * u);
    }
  }
  float accx = ax0 + ax1, accr = ar0 + ar1;
  if (lane < NS) m[node * 96 + lane] = packsplit(accr);
  m[node * 96 + NS + lane] = packsplit(accx);
}

// ---------------- batchnorm stats: stage 1 (vectorized, 512 blocks) ----------
template <int LD>
__global__ __launch_bounds__(256) void colstats2_kernel(const unsigned* __restrict__ X,
                                                        float* __restrict__ P) {
  constexpr int CG = LD / 4;
  constexpr int RPB = 256 / CG;
  const int t = threadIdx.x;
  const int cg = t % CG, rin = t / CG;
  float s0 = 0, s1 = 0, s2 = 0, s3 = 0, q0 = 0, q1 = 0, q2 = 0, q3 = 0;
  if (rin < RPB) {
    for (int r = blockIdx.x * RPB + rin; r < NN; r += gridDim.x * RPB) {
      uint4 v = *(const uint4*)(X + (size_t)r * LD + cg * 4);
      float f0 = bfp2f(v.x), f1 = bfp2f(v.y), f2 = bfp2f(v.z), f3 = bfp2f(v.w);
      s0 += f0; q0 += f0 * f0;
      s1 += f1; q1 += f1 * f1;
      s2 += f2; q2 += f2 * f2;
      s3 += f3; q3 += f3 * f3;
    }
  }
  __shared__ float sh[256][8];
  sh[t][0] = s0; sh[t][1] = s1; sh[t][2] = s2; sh[t][3] = s3;
  sh[t][4] = q0; sh[t][5] = q1; sh[t][6] = q2; sh[t][7] = q3;
  __syncthreads();
  if (rin == 0) {
#pragma unroll
    for (int rr = 1; rr < RPB; rr++) {
      const float* o = sh[rr * CG + cg];
      s0 += o[0]; s1 += o[1]; s2 += o[2]; s3 += o[3];
      q0 += o[4]; q1 += o[5]; q2 += o[6]; q3 += o[7];
    }
    float* Pb = P + blockIdx.x * 512;
    Pb[cg * 4 + 0] = s0; Pb[cg * 4 + 1] = s1; Pb[cg * 4 + 2] = s2; Pb[cg * 4 + 3] = s3;
    Pb[256 + cg * 4 + 0] = q0; Pb[256 + cg * 4 + 1] = q1;
    Pb[256 + cg * 4 + 2] = q2; Pb[256 + cg * 4 + 3] = q3;
  }
}

// ---------------- batchnorm stats: stage 2 (one block per column) ------------
__global__ __launch_bounds__(256) void bnfinal2_kernel(const float* __restrict__ P, int nblk,
                                                       const float* __restrict__ g,
                                                       const float* __restrict__ b, int ncols,
                                                       float* __restrict__ na,
                                                       float* __restrict__ nb) {
  int c = blockIdx.x;
  int t = threadIdx.x;
  float s = 0.f, q = 0.f;
  for (int i = t; i < nblk; i += 256) {
    s += P[i * 512 + c];
    q += P[i * 512 + 256 + c];
  }
#pragma unroll
  for (int off = 32; off > 0; off >>= 1) {
    s += __shfl_down(s, off, 64);
    q += __shfl_down(q, off, 64);
  }
  __shared__ float ws[4], wq[4];
  if ((t & 63) == 0) { ws[t >> 6] = s; wq[t >> 6] = q; }
  __syncthreads();
  if (t == 0) {
    s = ws[0] + ws[1] + ws[2] + ws[3];
    q = wq[0] + wq[1] + wq[2] + wq[3];
    if (c < ncols) {
      float mean = s / (float)NN;
      float var = q / (float)NN - mean * mean;
      float a = g[c] * rsqrtf(var + 1e-5f);
      na[c] = a;
      nb[c] = b[c] - mean * a;
    } else {
      na[c] = 0.f;  // pad cols -> BN-applied value 0
      nb[c] = 0.f;
    }
  }
}

// ---------------- BN apply: pair -> pre-normalized bf16 hi plane only --------
template <int LD>
__global__ __launch_bounds__(256) void bnapply_kernel(const unsigned* __restrict__ Xp,
                                                      const float* __restrict__ na,
                                                      const float* __restrict__ nb,
                                                      short* __restrict__ Xh) {
  int idx = blockIdx.x * 256 + threadIdx.x;  // over NP * LD/4
  if (idx >= NP * (LD / 4)) return;
  int row = idx / (LD / 4);
  int cg = (idx - row * (LD / 4)) * 4;
  short4b h;
  if (row < NN) {
    uint4 v = *(const uint4*)(Xp + (size_t)row * LD + cg);
    unsigned arr[4] = {v.x, v.y, v.z, v.w};
#pragma unroll
    for (int e = 0; e < 4; e++) {
      float f = bfp2f(arr[e]) * na[cg + e] + nb[cg + e];
      h[e] = (short)f2bf(f);
    }
  } else {
    h = (short4b){0, 0, 0, 0};
  }
  *(short4b*)(Xh + (size_t)row * LD + cg) = h;
}

// ---------------- fused MLP kernel ----------------
// 64-node tile, 4 waves splitting N {4,3,3,3}x16, acc[4][4]. Activations in LDS
// as a single bf16 hi plane. Weights = global hi/lo planes (L2-hot), with
// EXPLICIT one-iter register prefetch (bhn/bln) so B-load latency overlaps the
// MFMAs of the current iter. __launch_bounds__(256,3): ~170 unified regs/wave
// (R11's (256,4) starved the pipeliner at 128 -> serialized loads); grid is
// 782 blocks = ~3/CU so 3 blocks/CU is the occupancy reality anyway.
// 2-term split precision: acc += ah*bh + ah*bl. NaN guard: epi zeroes LDS cols
// [208,216) of every row + 16-short tail (R10 lesson: NaN*0=NaN in MFMA).
template <bool READOUT>
__global__ __launch_bounds__(256, 3) void fused_kernel(
    const short* __restrict__ Agh, int glda,
    const short* __restrict__ W1h, const short* __restrict__ W1l,
    const short* __restrict__ W2h, const short* __restrict__ W2l,
    const short* __restrict__ W3h, const short* __restrict__ W3l,
    const short* __restrict__ W4h, const short* __restrict__ W4l,
    const float* __restrict__ b1, const float* __restrict__ b2,
    const float* __restrict__ b3, const float* __restrict__ b4,
    unsigned* __restrict__ xp, short* __restrict__ xq, int t,
    const float* __restrict__ w4ro, const int* __restrict__ mol,
    float* __restrict__ out) {
  __shared__ short ldsH[64 * SP + 16];
  const int tid = threadIdx.x;
  const int wave = tid >> 6, lane = tid & 63, ln = lane & 15, quad = lane >> 4;
  const int bm = blockIdx.x * 64;
  const int ntile = (wave == 0) ? 4 : 3;
  const int n0col = (wave == 0) ? 0 : 16 + wave * 48;  // 0, 64, 112, 160

  if (tid < 16) ldsH[64 * SP + tid] = 0;  // zero tail for row-63 k-overread

  f32x4 acc[4][4];

  auto layer = [&](auto ga_tag, const short* __restrict__ Wh,
                   const short* __restrict__ Wl, int Kpad, int KP) {
    constexpr bool GA = decltype(ga_tag)::value;
#pragma unroll
    for (int i = 0; i < 4; i++)
#pragma unroll
      for (int j = 0; j < 4; j++) acc[i][j] = (f32x4){0.f, 0.f, 0.f, 0.f};

    short8b bhc[4], blc[4];
#pragma unroll
    for (int j = 0; j < 4; j++)
      if (j < ntile) {
        const size_t o = (size_t)(n0col + j * 16 + ln) * Kpad + quad * 8;
        bhc[j] = *(const short8b*)(Wh + o);
        blc[j] = *(const short8b*)(Wl + o);
      }
    for (int k0 = 0; k0 < KP; k0 += 32) {
      // A fragments for this iter (LDS or global)
      short8b ah[4];
#pragma unroll
      for (int i = 0; i < 4; i++) {
        int r = i * 16 + ln;
        if constexpr (GA)
          ah[i] = *(const short8b*)(Agh + (size_t)(bm + r) * glda + k0 + quad * 8);
        else
          ah[i] = *(const short8b*)(ldsH + r * SP + k0 + quad * 8);
      }
      // prefetch next iter's B into separate regs (stays in flight over MFMAs)
      short8b bhn[4], bln[4];
      const int kn = k0 + 32;
      if (kn < KP) {
#pragma unroll
        for (int j = 0; j < 4; j++)
          if (j < ntile) {
            const size_t o = (size_t)(n0col + j * 16 + ln) * Kpad + kn + quad * 8;
            bhn[j] = *(const short8b*)(Wh + o);
            bln[j] = *(const short8b*)(Wl + o);
          }
      }
#pragma unroll
      for (int j = 0; j < 4; j++)
        if (j < ntile)
#pragma unroll
          for (int i = 0; i < 4; i++) {
            acc[i][j] = __builtin_amdgcn_mfma_f32_16x16x32_bf16(ah[i], bhc[j], acc[i][j], 0, 0, 0);
            acc[i][j] = __builtin_amdgcn_mfma_f32_16x16x32_bf16(ah[i], blc[j], acc[i][j], 0, 0, 0);
          }
      if (kn < KP) {
#pragma unroll
        for (int j = 0; j < 4; j++)
          if (j < ntile) { bhc[j] = bhn[j]; blc[j] = bln[j]; }
      }
    }
  };

  // epilogue: relu(acc+bias) -> hi plane; zero cols [208,216) of every row
  auto epi = [&](const float* __restrict__ bias) {
    __syncthreads();
#pragma unroll
    for (int i = 0; i < 4; i++)
#pragma unroll
      for (int j = 0; j < 4; j++)
        if (j < ntile)
#pragma unroll
          for (int r = 0; r < 4; r++) {
            int row = i * 16 + quad * 4 + r;
            int col = n0col + j * 16 + ln;
            float v = acc[i][j][r] + (col < HH ? bias[col] : 0.f);
            v = fmaxf(v, 0.f);
            ldsH[row * SP + col] = (short)f2bf(v);
          }
    {  // NaN guard: cols 208..215 (4 threads/row x 1 dword)
      int row = tid >> 2;
      *(int*)(ldsH + row * SP + 208 + (tid & 3) * 2) = 0;
    }
    __syncthreads();
  };

  if (!READOUT) {
    layer(std::true_type{}, W1h, W1l, 96, 96);
    epi(b1);
    layer(std::false_type{}, W2h, W2l, 224, 224);
    epi(b2);
    layer(std::false_type{}, W3h, W3l, 224, 224);
    epi(b3);
    // ---- L4 (200->64): wave w -> cols w*16..+15, B prefetched ----
    f32x4 a4[4];
#pragma unroll
    for (int i = 0; i < 4; i++) a4[i] = (f32x4){0.f, 0.f, 0.f, 0.f};
    short8b bhc, blc;
    {
      const size_t o = (size_t)(wave * 16 + ln) * 224 + quad * 8;
      bhc = *(const short8b*)(W4h + o);
      blc = *(const short8b*)(W4l + o);
    }
    for (int k0 = 0; k0 < 224; k0 += 32) {
      short8b ah[4];
#pragma unroll
      for (int i = 0; i < 4; i++) {
        int r = i * 16 + ln;
        ah[i] = *(const short8b*)(ldsH + r * SP + k0 + quad * 8);
      }
      short8b bhn, bln;
      const int kn = k0 + 32;
      if (kn < 224) {
        const size_t o = (size_t)(wave * 16 + ln) * 224 + kn + quad * 8;
        bhn = *(const short8b*)(W4h + o);
        bln = *(const short8b*)(W4l + o);
      }
#pragma unroll
      for (int i = 0; i < 4; i++) {
        a4[i] = __builtin_amdgcn_mfma_f32_16x16x32_bf16(ah[i], bhc, a4[i], 0, 0, 0);
        a4[i] = __builtin_amdgcn_mfma_f32_16x16x32_bf16(ah[i], blc, a4[i], 0, 0, 0);
      }
      if (kn < 224) { bhc = bhn; blc = bln; }
    }
    // x-update: x[t+1] = x[t] + 0.1*(h3@W4 + b4); also maintain hi-plane xq
#pragma unroll
    for (int i = 0; i < 4; i++)
#pragma unroll
      for (int r = 0; r < 4; r++) {
        int grow = bm + i * 16 + quad * 4 + r;
        int col = wave * 16 + ln;
        if (grow < NN) {
          float v = a4[i][r] + b4[col];
          size_t base = (size_t)grow * RD;
          float old = bfp2f(xp[base + (size_t)t * ED + col]);
          unsigned pk = packsplit(old + 0.1f * v);
          xp[base + (size_t)(t + 1) * ED + col] = pk;
          xq[base + (size_t)(t + 1) * ED + col] = (short)(pk & 0xffffu);
        }
      }
  } else {
    layer(std::true_type{}, W1h, W1l, 256, 256);
    epi(b1);
    layer(std::false_type{}, W2h, W2l, 224, 224);
    epi(b2);
    layer(std::false_type{}, W3h, W3l, 224, 224);
    epi(b3);
    // fused final layer (200->1) + molecule segment-sum: 4 threads per row
    int row = tid >> 2;
    int grow = bm + row;
    float s = 0.f;
    for (int c = (tid & 3); c < HH; c += 4)
      s += ubf2f((unsigned short)ldsH[row * SP + c]) * w4ro[c];
    s += __shfl_xor(s, 1, 64);
    s += __shfl_xor(s, 2, 64);
    if ((tid & 3) == 0 && grow < NN) atomicAdd(&out[mol[grow]], s + b4[0]);
  }
}

// ---------------- host launcher ----------------
extern "C" void kernel_launch(void* const* d_in, const int* in_sizes, int n_in,
                              void* d_out, int out_size, void* d_ws, size_t ws_size,
                              hipStream_t stream) {
  const int* z_i = (const int*)d_in[0];
  const int* e_src = (const int*)d_in[1];
  const int* e_snk = ((const int*)d_in[1]) + EE;
  const float* dist = (const float*)d_in[2];
  const int* mol = (const int*)d_in[3];
  const float* emb = (const float*)d_in[4];
  const float* up_bn_g = (const float*)d_in[5];
  const float* up_bn_b = (const float*)d_in[6];
  const float* up_w1 = (const float*)d_in[7];
  const float* up_b1 = (const float*)d_in[8];
  const float* up_w2 = (const float*)d_in[9];
  const float* up_b2 = (const float*)d_in[10];
  const float* up_w3 = (const float*)d_in[11];
  const float* up_b3 = (const float*)d_in[12];
  const float* up_w4 = (const float*)d_in[13];
  const float* up_b4 = (const float*)d_in[14];
  const float* ro_bn_g = (const float*)d_in[15];
  const float* ro_bn_b = (const float*)d_in[16];
  const float* ro_w1 = (const float*)d_in[17];
  const float* ro_b1 = (const float*)d_in[18];
  const float* ro_w2 = (const float*)d_in[19];
  const float* ro_b2 = (const float*)d_in[20];
  const float* ro_w3 = (const float*)d_in[21];
  const float* ro_b3 = (const float*)d_in[22];
  const float* ro_w4 = (const float*)d_in[23];
  const float* ro_b4 = (const float*)d_in[24];
  float* out = (float*)d_out;

  char* p = (char*)d_ws;
  auto alloc = [&](size_t bytes) {
    void* r = (void*)p;
    p += (bytes + 255) & ~(size_t)255;
    return r;
  };
  unsigned* x_p = (unsigned*)alloc((size_t)NN * RD * 4);   // fp32-equiv pair
  short* x_q = (short*)alloc((size_t)NN * RD * 2);         // x hi plane (gather reads)
  unsigned* m_p = (unsigned*)alloc((size_t)NN * 96 * 4);
  short* mh = (short*)alloc((size_t)NP * 96 * 2);          // BN-applied m hi plane
  short* xh = (short*)alloc((size_t)NP * RD * 2);          // BN-applied x hi plane
  int* ssink = (int*)alloc((size_t)EE * 4);
  float* sdist = (float*)alloc((size_t)EE * 4);
  int* offs = (int*)alloc((size_t)(NN + 1) * 4);
  int* deg = (int*)alloc((size_t)NN * 4);
  int* cursor = (int*)alloc((size_t)NN * 4);
  float* P = (float*)alloc((size_t)NPB2 * 512 * 4);
  float* na = (float*)alloc(256 * 4);
  float* nb = (float*)alloc(256 * 4);
  // weight planes (transposed, padded)
  short* w1h = (short*)alloc((size_t)TT * 208 * 96 * 2);
  short* w1l = (short*)alloc((size_t)TT * 208 * 96 * 2);
  short* w2h = (short*)alloc((size_t)TT * 208 * 224 * 2);
  short* w2l = (short*)alloc((size_t)TT * 208 * 224 * 2);
  short* w3h = (short*)alloc((size_t)TT * 208 * 224 * 2);
  short* w3l = (short*)alloc((size_t)TT * 208 * 224 * 2);
  short* w4h = (short*)alloc((size_t)TT * 64 * 224 * 2);
  short* w4l = (short*)alloc((size_t)TT * 64 * 224 * 2);
  short* r1h = (short*)alloc((size_t)208 * 256 * 2);
  short* r1l = (short*)alloc((size_t)208 * 256 * 2);
  short* r2h = (short*)alloc((size_t)208 * 224 * 2);
  short* r2l = (short*)alloc((size_t)208 * 224 * 2);
  short* r3h = (short*)alloc((size_t)208 * 224 * 2);
  short* r3l = (short*)alloc((size_t)208 * 224 * 2);

  hipMemsetAsync(deg, 0, (size_t)NN * 4, stream);
  hipMemsetAsync(out, 0, (size_t)NMOL * 4, stream);

  WDs descs;
  descs.d[0] = {up_w1, w1h, w1l, MD, HH, 96, 208, TT};
  descs.d[1] = {up_w2, w2h, w2l, HH, HH, 224, 208, TT};
  descs.d[2] = {up_w3, w3h, w3l, HH, HH, 224, 208, TT};
  descs.d[3] = {up_w4, w4h, w4l, HH, ED, 224, 64, TT};
  descs.d[4] = {ro_w1, r1h, r1l, RD, HH, 256, 208, 1};
  descs.d[5] = {ro_w2, r2h, r2l, HH, HH, 224, 208, 1};
  descs.d[6] = {ro_w3, r3h, r3l, HH, HH, 224, 208, 1};
  wprep_kernel<<<dim3(546, 7), 256, 0, stream>>>(descs);

  emb_kernel<<<(NN * ED + 255) / 256, 256, 0, stream>>>(z_i, emb, x_p, x_q);
  hist_kernel<<<(EE + 255) / 256, 256, 0, stream>>>(e_src, deg);
  scan_kernel<<<1, 1024, 0, stream>>>(deg, offs, cursor);
  scatter_kernel<<<(EE + 255) / 256, 256, 0, stream>>>(e_src, e_snk, dist, cursor, ssink, sdist);

  const int gM = NP / 64;  // 782

  for (int t = 0; t < TT; t++) {
    gather_kernel<<<(NN + 3) / 4, 256, 0, stream>>>(offs, ssink, sdist, x_q, t * ED, m_p);
    colstats2_kernel<96><<<NPB2, 256, 0, stream>>>(m_p, P);
    bnfinal2_kernel<<<256, 256, 0, stream>>>(P, NPB2, up_bn_g + t * MD, up_bn_b + t * MD, MD,
                                             na, nb);
    bnapply_kernel<96><<<(NP * 24 + 255) / 256, 256, 0, stream>>>(m_p, na, nb, mh);
    fused_kernel<false><<<gM, 256, 0, stream>>>(
        mh, 96,
        w1h + (size_t)t * 208 * 96, w1l + (size_t)t * 208 * 96,
        w2h + (size_t)t * 208 * 224, w2l + (size_t)t * 208 * 224,
        w3h + (size_t)t * 208 * 224, w3l + (size_t)t * 208 * 224,
        w4h + (size_t)t * 64 * 224, w4l + (size_t)t * 64 * 224,
        up_b1 + t * HH, up_b2 + t * HH, up_b3 + t * HH, up_b4 + t * ED,
        x_p, x_q, t, nullptr, nullptr, nullptr);
  }

  colstats2_kernel<256><<<NPB2, 256, 0, stream>>>(x_p, P);
  bnfinal2_kernel<<<256, 256, 0, stream>>>(P, NPB2, ro_bn_g, ro_bn_b, RD, na, nb);
  bnapply_kernel<256><<<(NP * 64 + 255) / 256, 256, 0, stream>>>(x_p, na, nb, xh);
  fused_kernel<true><<<gM, 256, 0, stream>>>(
      xh, 256,
      r1h, r1l, r2h, r2l, r3h, r3l, nullptr, nullptr,
      ro_b1, ro_b2, ro_b3, ro_b4,
      nullptr, nullptr, 0, ro_w4, mol, out);

  (void)in_sizes; (void)n_in; (void)out_size; (void)ws_size;
}

// Round 13
// 860.557 us; speedup vs baseline: 1.1323x; 1.1323x over previous
//
#include <hip/hip_runtime.h>
#include <hip/hip_bf16.h>
#include <type_traits>

#define NN 50000
#define NP 50048   // NN padded to 128*391
#define EE 800000
#define TT 3
#define ED 64
#define NS 23
#define MD 87
#define HH 200
#define NMOL 2048
#define RD 256

#define SP 216     // LDS hi-plane stride (shorts)
#define NPB2 512   // colstats partial blocks

typedef __attribute__((ext_vector_type(8))) short short8b;
typedef __attribute__((ext_vector_type(4))) short short4b;
typedef __attribute__((ext_vector_type(4))) float f32x4;

// ---- bf16 helpers ----
__device__ __forceinline__ unsigned short f2bf(float f) {
  unsigned u = __float_as_uint(f);
  return (unsigned short)((u + 0x7fffu + ((u >> 16) & 1u)) >> 16);
}
__device__ __forceinline__ float ubf2f(unsigned short h) {
  return __uint_as_float(((unsigned)h) << 16);
}
// interleaved pair in one u32: low16 = hi-bf16, high16 = lo-bf16 (fp32-equivalent)
__device__ __forceinline__ float bfp2f(unsigned p) {
  return __uint_as_float(p << 16) + __uint_as_float(p & 0xffff0000u);
}
__device__ __forceinline__ unsigned packsplit(float v) {
  unsigned short h = f2bf(v);
  unsigned short l = f2bf(v - ubf2f(h));
  return (unsigned)h | ((unsigned)l << 16);
}

// ---------------- weight prep: fp32 [T][K][N] -> bf16 hi/lo planes [T][Npad][Kpad] ----
struct WD { const float* src; short* dh; short* dl; int K, N, Kpad, Npad, T; };
struct WDs { WD d[7]; };

__global__ __launch_bounds__(256) void wprep_kernel(WDs W) {
  WD w = W.d[blockIdx.y];
  int per = w.Npad * w.Kpad;
  int total = w.T * per;
  for (int idx = blockIdx.x * 256 + threadIdx.x; idx < total; idx += gridDim.x * 256) {
    int t = idx / per;
    int r = idx - t * per;
    int n = r / w.Kpad;
    int k = r - n * w.Kpad;
    float v = 0.f;
    if (k < w.K && n < w.N) v = w.src[((size_t)t * w.K + k) * w.N + n];
    unsigned short h = f2bf(v);
    unsigned short l = f2bf(v - ubf2f(h));
    w.dh[idx] = (short)h;
    w.dl[idx] = (short)l;
  }
}

// ---------------- embedding -> x slice 0 (pair + hi plane) ----------------
__global__ __launch_bounds__(256) void emb_kernel(const int* __restrict__ z,
                                                  const float* __restrict__ emb,
                                                  unsigned* __restrict__ xp,
                                                  short* __restrict__ xq) {
  int idx = blockIdx.x * 256 + threadIdx.x;
  if (idx >= NN * ED) return;
  int i = idx >> 6, d = idx & 63;
  unsigned pk = packsplit(emb[z[i] * ED + d]);
  xp[(size_t)i * RD + d] = pk;
  xq[(size_t)i * RD + d] = (short)(pk & 0xffffu);
}

// ---------------- CSR build ----------------
__global__ __launch_bounds__(256) void hist_kernel(const int* __restrict__ src,
                                                   int* __restrict__ deg) {
  int e = blockIdx.x * 256 + threadIdx.x;
  if (e < EE) atomicAdd(&deg[src[e]], 1);
}

__global__ __launch_bounds__(1024) void scan_kernel(const int* __restrict__ deg,
                                                    int* __restrict__ offs,
                                                    int* __restrict__ cursor) {
  __shared__ int sh[1024];
  int tid = threadIdx.x;
  const int CH = (NN + 1023) / 1024;
  int s0 = tid * CH, s1 = s0 + CH;
  if (s1 > NN) s1 = NN;
  int sum = 0;
  for (int i = s0; i < s1; i++) sum += deg[i];
  sh[tid] = sum;
  __syncthreads();
  for (int off = 1; off < 1024; off <<= 1) {
    int t = (tid >= off) ? sh[tid - off] : 0;
    __syncthreads();
    sh[tid] += t;
    __syncthreads();
  }
  int base = sh[tid] - sum;
  for (int i = s0; i < s1; i++) {
    offs[i] = base;
    cursor[i] = base;
    base += deg[i];
  }
  if (tid == 1023) offs[NN] = sh[1023];
}

__global__ __launch_bounds__(256) void scatter_kernel(const int* __restrict__ src,
                                                      const int* __restrict__ snk,
                                                      const float* __restrict__ dist,
                                                      int* __restrict__ cursor,
                                                      int* __restrict__ ssink,
                                                      float* __restrict__ sdist) {
  int e = blockIdx.x * 256 + threadIdx.x;
  if (e >= EE) return;
  int p = atomicAdd(&cursor[src[e]], 1);
  ssink[p] = snk[e];
  sdist[p] = dist[e];
}

// ---------------- message gather: one wave per node, hi-plane reads ----------
__global__ __launch_bounds__(256) void gather_kernel(const int* __restrict__ offs,
                                                     const int* __restrict__ ssink,
                                                     const float* __restrict__ sdist,
                                                     const short* __restrict__ xq,
                                                     int toff, unsigned* __restrict__ m) {
  int node = blockIdx.x * 4 + (threadIdx.x >> 6);
  int lane = threadIdx.x & 63;
  if (node >= NN) return;
  float shift = (float)(0.8 + 0.1 * (double)lane);
  int e0 = offs[node], e1 = offs[node + 1];
  float ax0 = 0.f, ax1 = 0.f, ar0 = 0.f, ar1 = 0.f;
  int j = e0;
  for (; j + 4 <= e1; j += 4) {
    int s0 = ssink[j], s1 = ssink[j + 1], s2 = ssink[j + 2], s3 = ssink[j + 3];
    float d0 = sdist[j], d1 = sdist[j + 1], d2 = sdist[j + 2], d3 = sdist[j + 3];
    float x0 = ubf2f((unsigned short)xq[(size_t)s0 * RD + toff + lane]);
    float x1 = ubf2f((unsigned short)xq[(size_t)s1 * RD + toff + lane]);
    float x2 = ubf2f((unsigned short)xq[(size_t)s2 * RD + toff + lane]);
    float x3 = ubf2f((unsigned short)xq[(size_t)s3 * RD + toff + lane]);
    ax0 += x0 + x2;
    ax1 += x1 + x3;
    if (lane < NS) {
      float u0 = d0 - shift, u1 = d1 - shift, u2 = d2 - shift, u3 = d3 - shift;
      ar0 += __expf(-u0 * u0) + __expf(-u2 * u2);
      ar1 += __expf(-u1 * u1) + __expf(-u3 * u3);
    }
  }
  for (; j < e1; j++) {
    int s = ssink[j];
    float d = sdist[j];
    ax0 += ubf2f((unsigned short)xq[(size_t)s * RD + toff + lane]);
    if (lane < NS) {
      float u = d - shift;
      ar0 += __expf(-u * u);
    }
  }
  float accx = ax0 + ax1, accr = ar0 + ar1;
  if (lane < NS) m[node * 96 + lane] = packsplit(accr);
  m[node * 96 + NS + lane] = packsplit(accx);
}

// ---------------- batchnorm stats: stage 1 (vectorized, 512 blocks) ----------
template <int LD>
__global__ __launch_bounds__(256) void colstats2_kernel(const unsigned* __restrict__ X,
                                                        float* __restrict__ P) {
  constexpr int CG = LD / 4;
  constexpr int RPB = 256 / CG;
  const int t = threadIdx.x;
  const int cg = t % CG, rin = t / CG;
  float s0 = 0, s1 = 0, s2 = 0, s3 = 0, q0 = 0, q1 = 0, q2 = 0, q3 = 0;
  if (rin < RPB) {
    for (int r = blockIdx.x * RPB + rin; r < NN; r += gridDim.x * RPB) {
      uint4 v = *(const uint4*)(X + (size_t)r * LD + cg * 4);
      float f0 = bfp2f(v.x), f1 = bfp2f(v.y), f2 = bfp2f(v.z), f3 = bfp2f(v.w);
      s0 += f0; q0 += f0 * f0;
      s1 += f1; q1 += f1 * f1;
      s2 += f2; q2 += f2 * f2;
      s3 += f3; q3 += f3 * f3;
    }
  }
  __shared__ float sh[256][8];
  sh[t][0] = s0; sh[t][1] = s1; sh[t][2] = s2; sh[t][3] = s3;
  sh[t][4] = q0; sh[t][5] = q1; sh[t][6] = q2; sh[t][7] = q3;
  __syncthreads();
  if (rin == 0) {
#pragma unroll
    for (int rr = 1; rr < RPB; rr++) {
      const float* o = sh[rr * CG + cg];
      s0 += o[0]; s1 += o[1]; s2 += o[2]; s3 += o[3];
      q0 += o[4]; q1 += o[5]; q2 += o[6]; q3 += o[7];
    }
    float* Pb = P + blockIdx.x * 512;
    Pb[cg * 4 + 0] = s0; Pb[cg * 4 + 1] = s1; Pb[cg * 4 + 2] = s2; Pb[cg * 4 + 3] = s3;
    Pb[256 + cg * 4 + 0] = q0; Pb[256 + cg * 4 + 1] = q1;
    Pb[256 + cg * 4 + 2] = q2; Pb[256 + cg * 4 + 3] = q3;
  }
}

// ---------------- batchnorm stats: stage 2 (one block per column) ------------
__global__ __launch_bounds__(256) void bnfinal2_kernel(const float* __restrict__ P, int nblk,
                                                       const float* __restrict__ g,
                                                       const float* __restrict__ b, int ncols,
                                                       float* __restrict__ na,
                                                       float* __restrict__ nb) {
  int c = blockIdx.x;
  int t = threadIdx.x;
  float s = 0.f, q = 0.f;
  for (int i = t; i < nblk; i += 256) {
    s += P[i * 512 + c];
    q += P[i * 512 + 256 + c];
  }
#pragma unroll
  for (int off = 32; off > 0; off >>= 1) {
    s += __shfl_down(s, off, 64);
    q += __shfl_down(q, off, 64);
  }
  __shared__ float ws[4], wq[4];
  if ((t & 63) == 0) { ws[t >> 6] = s; wq[t >> 6] = q; }
  __syncthreads();
  if (t == 0) {
    s = ws[0] + ws[1] + ws[2] + ws[3];
    q = wq[0] + wq[1] + wq[2] + wq[3];
    if (c < ncols) {
      float mean = s / (float)NN;
      float var = q / (float)NN - mean * mean;
      float a = g[c] * rsqrtf(var + 1e-5f);
      na[c] = a;
      nb[c] = b[c] - mean * a;
    } else {
      na[c] = 0.f;  // pad cols -> BN-applied value 0
      nb[c] = 0.f;
    }
  }
}

// ---------------- BN apply: pair -> pre-normalized bf16 hi plane only --------
template <int LD>
__global__ __launch_bounds__(256) void bnapply_kernel(const unsigned* __restrict__ Xp,
                                                      const float* __restrict__ na,
                                                      const float* __restrict__ nb,
                                                      short* __restrict__ Xh) {
  int idx = blockIdx.x * 256 + threadIdx.x;  // over NP * LD/4
  if (idx >= NP * (LD / 4)) return;
  int row = idx / (LD / 4);
  int cg = (idx - row * (LD / 4)) * 4;
  short4b h;
  if (row < NN) {
    uint4 v = *(const uint4*)(Xp + (size_t)row * LD + cg);
    unsigned arr[4] = {v.x, v.y, v.z, v.w};
#pragma unroll
    for (int e = 0; e < 4; e++) {
      float f = bfp2f(arr[e]) * na[cg + e] + nb[cg + e];
      h[e] = (short)f2bf(f);
    }
  } else {
    h = (short4b){0, 0, 0, 0};
  }
  *(short4b*)(Xh + (size_t)row * LD + cg) = h;
}

// ---------------- fused MLP kernel ----------------
// 128-node tile, 512 threads = 8 waves in 2(M) x 4(N); acc[4][4] per wave
// (same MFMA:B-load ratio as R11, but 2x rows/block -> half the chip-wide
// B re-fetch traffic, and 2 blocks/CU x 8 waves = 16 waves/CU for latency
// hiding). Activations in LDS as a single bf16 hi plane (55 KB). Weights =
// global hi/lo planes (L2-hot), plain loads (R12 showed explicit register
// prefetch is defeated by the compiler and regresses). 2-term split
// precision: acc += ah*bh + ah*bl. NaN guard: epi zeroes LDS cols [208,216)
// of every row + 16-short tail (R10 lesson: NaN*0=NaN in MFMA).
template <bool READOUT>
__global__ __launch_bounds__(512, 4) void fused_kernel(
    const short* __restrict__ Agh, int glda,
    const short* __restrict__ W1h, const short* __restrict__ W1l,
    const short* __restrict__ W2h, const short* __restrict__ W2l,
    const short* __restrict__ W3h, const short* __restrict__ W3l,
    const short* __restrict__ W4h, const short* __restrict__ W4l,
    const float* __restrict__ b1, const float* __restrict__ b2,
    const float* __restrict__ b3, const float* __restrict__ b4,
    unsigned* __restrict__ xp, short* __restrict__ xq, int t,
    const float* __restrict__ w4ro, const int* __restrict__ mol,
    float* __restrict__ out) {
  __shared__ short ldsH[128 * SP + 16];
  const int tid = threadIdx.x;
  const int wave = tid >> 6, lane = tid & 63, ln = lane & 15, quad = lane >> 4;
  const int wm = wave >> 2;   // M half: rows wm*64 .. wm*64+63
  const int wn = wave & 3;    // N quarter
  const int bm = blockIdx.x * 128;
  const int ntile = (wn == 0) ? 4 : 3;
  const int n0col = (wn == 0) ? 0 : 16 + wn * 48;  // 0, 64, 112, 160

  if (tid < 16) ldsH[128 * SP + tid] = 0;  // zero tail for row-127 k-overread

  f32x4 acc[4][4];

  auto layer = [&](auto ga_tag, const short* __restrict__ Wh,
                   const short* __restrict__ Wl, int Kpad, int KP) {
    constexpr bool GA = decltype(ga_tag)::value;
#pragma unroll
    for (int i = 0; i < 4; i++)
#pragma unroll
      for (int j = 0; j < 4; j++) acc[i][j] = (f32x4){0.f, 0.f, 0.f, 0.f};
    for (int k0 = 0; k0 < KP; k0 += 32) {
      short8b ah[4], bh[4], bl[4];
#pragma unroll
      for (int i = 0; i < 4; i++) {
        int r = wm * 64 + i * 16 + ln;
        if constexpr (GA)
          ah[i] = *(const short8b*)(Agh + (size_t)(bm + r) * glda + k0 + quad * 8);
        else
          ah[i] = *(const short8b*)(ldsH + r * SP + k0 + quad * 8);
      }
#pragma unroll
      for (int j = 0; j < 4; j++)
        if (j < ntile) {
          const size_t o = (size_t)(n0col + j * 16 + ln) * Kpad + k0 + quad * 8;
          bh[j] = *(const short8b*)(Wh + o);
          bl[j] = *(const short8b*)(Wl + o);
        }
#pragma unroll
      for (int j = 0; j < 4; j++)
        if (j < ntile)
#pragma unroll
          for (int i = 0; i < 4; i++) {
            acc[i][j] = __builtin_amdgcn_mfma_f32_16x16x32_bf16(ah[i], bh[j], acc[i][j], 0, 0, 0);
            acc[i][j] = __builtin_amdgcn_mfma_f32_16x16x32_bf16(ah[i], bl[j], acc[i][j], 0, 0, 0);
          }
    }
  };

  // epilogue: relu(acc+bias) -> hi plane; zero cols [208,216) of every row
  auto epi = [&](const float* __restrict__ bias) {
    __syncthreads();
#pragma unroll
    for (int i = 0; i < 4; i++)
#pragma unroll
      for (int j = 0; j < 4; j++)
        if (j < ntile)
#pragma unroll
          for (int r = 0; r < 4; r++) {
            int row = wm * 64 + i * 16 + quad * 4 + r;
            int col = n0col + j * 16 + ln;
            float v = acc[i][j][r] + (col < HH ? bias[col] : 0.f);
            v = fmaxf(v, 0.f);
            ldsH[row * SP + col] = (short)f2bf(v);
          }
    {  // NaN guard: cols 208..215 (4 threads/row x 1 dword, 512 thr = 128 rows)
      int row = tid >> 2;
      *(int*)(ldsH + row * SP + 208 + (tid & 3) * 2) = 0;
    }
    __syncthreads();
  };

  if (!READOUT) {
    layer(std::true_type{}, W1h, W1l, 96, 96);
    epi(b1);
    layer(std::false_type{}, W2h, W2l, 224, 224);
    epi(b2);
    layer(std::false_type{}, W3h, W3l, 224, 224);
    epi(b3);
    // ---- L4 (200->64): wave (wm,wn) -> rows wm*64.., cols wn*16..+15 ----
    f32x4 a4[4];
#pragma unroll
    for (int i = 0; i < 4; i++) a4[i] = (f32x4){0.f, 0.f, 0.f, 0.f};
    for (int k0 = 0; k0 < 224; k0 += 32) {
      short8b ah[4], bh, bl;
#pragma unroll
      for (int i = 0; i < 4; i++) {
        int r = wm * 64 + i * 16 + ln;
        ah[i] = *(const short8b*)(ldsH + r * SP + k0 + quad * 8);
      }
      const size_t o = (size_t)(wn * 16 + ln) * 224 + k0 + quad * 8;
      bh = *(const short8b*)(W4h + o);
      bl = *(const short8b*)(W4l + o);
#pragma unroll
      for (int i = 0; i < 4; i++) {
        a4[i] = __builtin_amdgcn_mfma_f32_16x16x32_bf16(ah[i], bh, a4[i], 0, 0, 0);
        a4[i] = __builtin_amdgcn_mfma_f32_16x16x32_bf16(ah[i], bl, a4[i], 0, 0, 0);
      }
    }
    // x-update: x[t+1] = x[t] + 0.1*(h3@W4 + b4); also maintain hi-plane xq
#pragma unroll
    for (int i = 0; i < 4; i++)
#pragma unroll
      for (int r = 0; r < 4; r++) {
        int grow = bm + wm * 64 + i * 16 + quad * 4 + r;
        int col = wn * 16 + ln;
        if (grow < NN) {
          float v = a4[i][r] + b4[col];
          size_t base = (size_t)grow * RD;
          float old = bfp2f(xp[base + (size_t)t * ED + col]);
          unsigned pk = packsplit(old + 0.1f * v);
          xp[base + (size_t)(t + 1) * ED + col] = pk;
          xq[base + (size_t)(t + 1) * ED + col] = (short)(pk & 0xffffu);
        }
      }
  } else {
    layer(std::true_type{}, W1h, W1l, 256, 256);
    epi(b1);
    layer(std::false_type{}, W2h, W2l, 224, 224);
    epi(b2);
    layer(std::false_type{}, W3h, W3l, 224, 224);
    epi(b3);
    // fused final layer (200->1) + molecule segment-sum: 4 threads per row
    int row = tid >> 2;
    int grow = bm + row;
    float s = 0.f;
    for (int c = (tid & 3); c < HH; c += 4)
      s += ubf2f((unsigned short)ldsH[row * SP + c]) * w4ro[c];
    s += __shfl_xor(s, 1, 64);
    s += __shfl_xor(s, 2, 64);
    if ((tid & 3) == 0 && grow < NN) atomicAdd(&out[mol[grow]], s + b4[0]);
  }
}

// ---------------- host launcher ----------------
extern "C" void kernel_launch(void* const* d_in, const int* in_sizes, int n_in,
                              void* d_out, int out_size, void* d_ws, size_t ws_size,
                              hipStream_t stream) {
  const int* z_i = (const int*)d_in[0];
  const int* e_src = (const int*)d_in[1];
  const int* e_snk = ((const int*)d_in[1]) + EE;
  const float* dist = (const float*)d_in[2];
  const int* mol = (const int*)d_in[3];
  const float* emb = (const float*)d_in[4];
  const float* up_bn_g = (const float*)d_in[5];
  const float* up_bn_b = (const float*)d_in[6];
  const float* up_w1 = (const float*)d_in[7];
  const float* up_b1 = (const float*)d_in[8];
  const float* up_w2 = (const float*)d_in[9];
  const float* up_b2 = (const float*)d_in[10];
  const float* up_w3 = (const float*)d_in[11];
  const float* up_b3 = (const float*)d_in[12];
  const float* up_w4 = (const float*)d_in[13];
  const float* up_b4 = (const float*)d_in[14];
  const float* ro_bn_g = (const float*)d_in[15];
  const float* ro_bn_b = (const float*)d_in[16];
  const float* ro_w1 = (const float*)d_in[17];
  const float* ro_b1 = (const float*)d_in[18];
  const float* ro_w2 = (const float*)d_in[19];
  const float* ro_b2 = (const float*)d_in[20];
  const float* ro_w3 = (const float*)d_in[21];
  const float* ro_b3 = (const float*)d_in[22];
  const float* ro_w4 = (const float*)d_in[23];
  const float* ro_b4 = (const float*)d_in[24];
  float* out = (float*)d_out;

  char* p = (char*)d_ws;
  auto alloc = [&](size_t bytes) {
    void* r = (void*)p;
    p += (bytes + 255) & ~(size_t)255;
    return r;
  };
  unsigned* x_p = (unsigned*)alloc((size_t)NN * RD * 4);   // fp32-equiv pair
  short* x_q = (short*)alloc((size_t)NN * RD * 2);         // x hi plane (gather reads)
  unsigned* m_p = (unsigned*)alloc((size_t)NN * 96 * 4);
  short* mh = (short*)alloc((size_t)NP * 96 * 2);          // BN-applied m hi plane
  short* xh = (short*)alloc((size_t)NP * RD * 2);          // BN-applied x hi plane
  int* ssink = (int*)alloc((size_t)EE * 4);
  float* sdist = (float*)alloc((size_t)EE * 4);
  int* offs = (int*)alloc((size_t)(NN + 1) * 4);
  int* deg = (int*)alloc((size_t)NN * 4);
  int* cursor = (int*)alloc((size_t)NN * 4);
  float* P = (float*)alloc((size_t)NPB2 * 512 * 4);
  float* na = (float*)alloc(256 * 4);
  float* nb = (float*)alloc(256 * 4);
  // weight planes (transposed, padded)
  short* w1h = (short*)alloc((size_t)TT * 208 * 96 * 2);
  short* w1l = (short*)alloc((size_t)TT * 208 * 96 * 2);
  short* w2h = (short*)alloc((size_t)TT * 208 * 224 * 2);
  short* w2l = (short*)alloc((size_t)TT * 208 * 224 * 2);
  short* w3h = (short*)alloc((size_t)TT * 208 * 224 * 2);
  short* w3l = (short*)alloc((size_t)TT * 208 * 224 * 2);
  short* w4h = (short*)alloc((size_t)TT * 64 * 224 * 2);
  short* w4l = (short*)alloc((size_t)TT * 64 * 224 * 2);
  short* r1h = (short*)alloc((size_t)208 * 256 * 2);
  short* r1l = (short*)alloc((size_t)208 * 256 * 2);
  short* r2h = (short*)alloc((size_t)208 * 224 * 2);
  short* r2l = (short*)alloc((size_t)208 * 224 * 2);
  short* r3h = (short*)alloc((size_t)208 * 224 * 2);
  short* r3l = (short*)alloc((size_t)208 * 224 * 2);

  hipMemsetAsync(deg, 0, (size_t)NN * 4, stream);
  hipMemsetAsync(out, 0, (size_t)NMOL * 4, stream);

  WDs descs;
  descs.d[0] = {up_w1, w1h, w1l, MD, HH, 96, 208, TT};
  descs.d[1] = {up_w2, w2h, w2l, HH, HH, 224, 208, TT};
  descs.d[2] = {up_w3, w3h, w3l, HH, HH, 224, 208, TT};
  descs.d[3] = {up_w4, w4h, w4l, HH, ED, 224, 64, TT};
  descs.d[4] = {ro_w1, r1h, r1l, RD, HH, 256, 208, 1};
  descs.d[5] = {ro_w2, r2h, r2l, HH, HH, 224, 208, 1};
  descs.d[6] = {ro_w3, r3h, r3l, HH, HH, 224, 208, 1};
  wprep_kernel<<<dim3(546, 7), 256, 0, stream>>>(descs);

  emb_kernel<<<(NN * ED + 255) / 256, 256, 0, stream>>>(z_i, emb, x_p, x_q);
  hist_kernel<<<(EE + 255) / 256, 256, 0, stream>>>(e_src, deg);
  scan_kernel<<<1, 1024, 0, stream>>>(deg, offs, cursor);
  scatter_kernel<<<(EE + 255) / 256, 256, 0, stream>>>(e_src, e_snk, dist, cursor, ssink, sdist);

  const int gM = NP / 128;  // 391

  for (int t = 0; t < TT; t++) {
    gather_kernel<<<(NN + 3) / 4, 256, 0, stream>>>(offs, ssink, sdist, x_q, t * ED, m_p);
    colstats2_kernel<96><<<NPB2, 256, 0, stream>>>(m_p, P);
    bnfinal2_kernel<<<256, 256, 0, stream>>>(P, NPB2, up_bn_g + t * MD, up_bn_b + t * MD, MD,
                                             na, nb);
    bnapply_kernel<96><<<(NP * 24 + 255) / 256, 256, 0, stream>>>(m_p, na, nb, mh);
    fused_kernel<false><<<gM, 512, 0, stream>>>(
        mh, 96,
        w1h + (size_t)t * 208 * 96, w1l + (size_t)t * 208 * 96,
        w2h + (size_t)t * 208 * 224, w2l + (size_t)t * 208 * 224,
        w3h + (size_t)t * 208 * 224, w3l + (size_t)t * 208 * 224,
        w4h + (size_t)t * 64 * 224, w4l + (size_t)t * 64 * 224,
        up_b1 + t * HH, up_b2 + t * HH, up_b3 + t * HH, up_b4 + t * ED,
        x_p, x_q, t, nullptr, nullptr, nullptr);
  }

  colstats2_kernel<256><<<NPB2, 256, 0, stream>>>(x_p, P);
  bnfinal2_kernel<<<256, 256, 0, stream>>>(P, NPB2, ro_bn_g, ro_bn_b, RD, na, nb);
  bnapply_kernel<256><<<(NP * 64 + 255) / 256, 256, 0, stream>>>(x_p, na, nb, xh);
  fused_kernel<true><<<gM, 512, 0, stream>>>(
      xh, 256,
      r1h, r1l, r2h, r2l, r3h, r3l, nullptr, nullptr,
      ro_b1, ro_b2, ro_b3, ro_b4,
      nullptr, nullptr, 0, ro_w4, mol, out);

  (void)in_sizes; (void)n_in; (void)out_size; (void)ws_size;
}

// Round 14
// 765.043 us; speedup vs baseline: 1.2736x; 1.1248x over previous
//
#include <hip/hip_runtime.h>
#include <hip/hip_bf16.h>
#include <type_traits>

#define NN 50000
#define NP 50048   // NN padded to 128*391
#define EE 800000
#define TT 3
#define ED 64
#define NS 23
#define MD 87
#define HH 200
#define NMOL 2048
#define RD 256

#define SP 216     // LDS hi-plane stride (shorts)
#define NPB2 512   // colstats partial blocks
#define SNB ((NN + 255) / 256)  // 196 scan blocks

typedef __attribute__((ext_vector_type(8))) short short8b;
typedef __attribute__((ext_vector_type(4))) short short4b;
typedef __attribute__((ext_vector_type(4))) float f32x4;

// ---- bf16 helpers ----
__device__ __forceinline__ unsigned short f2bf(float f) {
  unsigned u = __float_as_uint(f);
  return (unsigned short)((u + 0x7fffu + ((u >> 16) & 1u)) >> 16);
}
__device__ __forceinline__ float ubf2f(unsigned short h) {
  return __uint_as_float(((unsigned)h) << 16);
}
// interleaved pair in one u32: low16 = hi-bf16, high16 = lo-bf16 (fp32-equivalent)
__device__ __forceinline__ float bfp2f(unsigned p) {
  return __uint_as_float(p << 16) + __uint_as_float(p & 0xffff0000u);
}
__device__ __forceinline__ unsigned packsplit(float v) {
  unsigned short h = f2bf(v);
  unsigned short l = f2bf(v - ubf2f(h));
  return (unsigned)h | ((unsigned)l << 16);
}

// ---------------- weight prep: fp32 [T][K][N] -> bf16 hi/lo planes [T][Npad][Kpad] ----
struct WD { const float* src; short* dh; short* dl; int K, N, Kpad, Npad, T; };
struct WDs { WD d[7]; };

__global__ __launch_bounds__(256) void wprep_kernel(WDs W) {
  WD w = W.d[blockIdx.y];
  int per = w.Npad * w.Kpad;
  int total = w.T * per;
  for (int idx = blockIdx.x * 256 + threadIdx.x; idx < total; idx += gridDim.x * 256) {
    int t = idx / per;
    int r = idx - t * per;
    int n = r / w.Kpad;
    int k = r - n * w.Kpad;
    float v = 0.f;
    if (k < w.K && n < w.N) v = w.src[((size_t)t * w.K + k) * w.N + n];
    unsigned short h = f2bf(v);
    unsigned short l = f2bf(v - ubf2f(h));
    w.dh[idx] = (short)h;
    w.dl[idx] = (short)l;
  }
}

// ---------------- embedding -> x slice 0 (pair + hi plane) ----------------
__global__ __launch_bounds__(256) void emb_kernel(const int* __restrict__ z,
                                                  const float* __restrict__ emb,
                                                  unsigned* __restrict__ xp,
                                                  short* __restrict__ xq) {
  int idx = blockIdx.x * 256 + threadIdx.x;
  if (idx >= NN * ED) return;
  int i = idx >> 6, d = idx & 63;
  unsigned pk = packsplit(emb[z[i] * ED + d]);
  xp[(size_t)i * RD + d] = pk;
  xq[(size_t)i * RD + d] = (short)(pk & 0xffffu);
}

// ---------------- CSR build ----------------
__global__ __launch_bounds__(256) void hist_kernel(const int* __restrict__ src,
                                                   int* __restrict__ deg) {
  int e = blockIdx.x * 256 + threadIdx.x;
  if (e < EE) atomicAdd(&deg[src[e]], 1);
}

// 3-stage parallel exclusive scan of deg[0..NN) (R13: single-block scan was
// the #1 dispatch at 110 us, 0.14% occupancy -- latency-bound serial chains).
__global__ __launch_bounds__(256) void scanA_kernel(const int* __restrict__ deg,
                                                    int* __restrict__ Psum) {
  int i = blockIdx.x * 256 + threadIdx.x;
  int v = (i < NN) ? deg[i] : 0;
#pragma unroll
  for (int off = 32; off > 0; off >>= 1) v += __shfl_down(v, off, 64);
  __shared__ int ws[4];
  if ((threadIdx.x & 63) == 0) ws[threadIdx.x >> 6] = v;
  __syncthreads();
  if (threadIdx.x == 0) Psum[blockIdx.x] = ws[0] + ws[1] + ws[2] + ws[3];
}

__global__ __launch_bounds__(256) void scanB_kernel(const int* __restrict__ Psum,
                                                    int* __restrict__ Poff) {
  __shared__ int sh[256];
  int t = threadIdx.x;
  int v = (t < SNB) ? Psum[t] : 0;
  sh[t] = v;
  __syncthreads();
  for (int off = 1; off < 256; off <<= 1) {
    int u = (t >= off) ? sh[t - off] : 0;
    __syncthreads();
    sh[t] += u;
    __syncthreads();
  }
  if (t < SNB) Poff[t] = sh[t] - v;  // exclusive
}

__global__ __launch_bounds__(256) void scanC_kernel(const int* __restrict__ deg,
                                                    const int* __restrict__ Poff,
                                                    int* __restrict__ offs,
                                                    int* __restrict__ cursor) {
  __shared__ int sh[256];
  int t = threadIdx.x;
  int i = blockIdx.x * 256 + t;
  int v = (i < NN) ? deg[i] : 0;
  sh[t] = v;
  __syncthreads();
  for (int off = 1; off < 256; off <<= 1) {
    int u = (t >= off) ? sh[t - off] : 0;
    __syncthreads();
    sh[t] += u;
    __syncthreads();
  }
  int excl = Poff[blockIdx.x] + sh[t] - v;
  if (i < NN) {
    offs[i] = excl;
    cursor[i] = excl;
    if (i == NN - 1) offs[NN] = excl + v;
  }
}

__global__ __launch_bounds__(256) void scatter_kernel(const int* __restrict__ src,
                                                      const int* __restrict__ snk,
                                                      const float* __restrict__ dist,
                                                      int* __restrict__ cursor,
                                                      int* __restrict__ ssink,
                                                      float* __restrict__ sdist) {
  int e = blockIdx.x * 256 + threadIdx.x;
  if (e >= EE) return;
  int p = atomicAdd(&cursor[src[e]], 1);
  ssink[p] = snk[e];
  sdist[p] = dist[e];
}

// ---------------- message gather: one wave per node, hi-plane reads ----------
__global__ __launch_bounds__(256) void gather_kernel(const int* __restrict__ offs,
                                                     const int* __restrict__ ssink,
                                                     const float* __restrict__ sdist,
                                                     const short* __restrict__ xq,
                                                     int toff, unsigned* __restrict__ m) {
  int node = blockIdx.x * 4 + (threadIdx.x >> 6);
  int lane = threadIdx.x & 63;
  if (node >= NN) return;
  float shift = (float)(0.8 + 0.1 * (double)lane);
  int e0 = offs[node], e1 = offs[node + 1];
  float ax0 = 0.f, ax1 = 0.f, ar0 = 0.f, ar1 = 0.f;
  int j = e0;
  for (; j + 4 <= e1; j += 4) {
    int s0 = ssink[j], s1 = ssink[j + 1], s2 = ssink[j + 2], s3 = ssink[j + 3];
    float d0 = sdist[j], d1 = sdist[j + 1], d2 = sdist[j + 2], d3 = sdist[j + 3];
    float x0 = ubf2f((unsigned short)xq[(size_t)s0 * RD + toff + lane]);
    float x1 = ubf2f((unsigned short)xq[(size_t)s1 * RD + toff + lane]);
    float x2 = ubf2f((unsigned short)xq[(size_t)s2 * RD + toff + lane]);
    float x3 = ubf2f((unsigned short)xq[(size_t)s3 * RD + toff + lane]);
    ax0 += x0 + x2;
    ax1 += x1 + x3;
    if (lane < NS) {
      float u0 = d0 - shift, u1 = d1 - shift, u2 = d2 - shift, u3 = d3 - shift;
      ar0 += __expf(-u0 * u0) + __expf(-u2 * u2);
      ar1 += __expf(-u1 * u1) + __expf(-u3 * u3);
    }
  }
  for (; j < e1; j++) {
    int s = ssink[j];
    float d = sdist[j];
    ax0 += ubf2f((unsigned short)xq[(size_t)s * RD + toff + lane]);
    if (lane < NS) {
      float u = d - shift;
      ar0 += __expf(-u * u);
    }
  }
  float accx = ax0 + ax1, accr = ar0 + ar1;
  if (lane < NS) m[node * 96 + lane] = packsplit(accr);
  m[node * 96 + NS + lane] = packsplit(accx);
}

// ---------------- batchnorm stats: stage 1 (vectorized, 512 blocks) ----------
template <int LD>
__global__ __launch_bounds__(256) void colstats2_kernel(const unsigned* __restrict__ X,
                                                        float* __restrict__ P) {
  constexpr int CG = LD / 4;
  constexpr int RPB = 256 / CG;
  const int t = threadIdx.x;
  const int cg = t % CG, rin = t / CG;
  float s0 = 0, s1 = 0, s2 = 0, s3 = 0, q0 = 0, q1 = 0, q2 = 0, q3 = 0;
  if (rin < RPB) {
    for (int r = blockIdx.x * RPB + rin; r < NN; r += gridDim.x * RPB) {
      uint4 v = *(const uint4*)(X + (size_t)r * LD + cg * 4);
      float f0 = bfp2f(v.x), f1 = bfp2f(v.y), f2 = bfp2f(v.z), f3 = bfp2f(v.w);
      s0 += f0; q0 += f0 * f0;
      s1 += f1; q1 += f1 * f1;
      s2 += f2; q2 += f2 * f2;
      s3 += f3; q3 += f3 * f3;
    }
  }
  __shared__ float sh[256][8];
  sh[t][0] = s0; sh[t][1] = s1; sh[t][2] = s2; sh[t][3] = s3;
  sh[t][4] = q0; sh[t][5] = q1; sh[t][6] = q2; sh[t][7] = q3;
  __syncthreads();
  if (rin == 0) {
#pragma unroll
    for (int rr = 1; rr < RPB; rr++) {
      const float* o = sh[rr * CG + cg];
      s0 += o[0]; s1 += o[1]; s2 += o[2]; s3 += o[3];
      q0 += o[4]; q1 += o[5]; q2 += o[6]; q3 += o[7];
    }
    float* Pb = P + blockIdx.x * 512;
    Pb[cg * 4 + 0] = s0; Pb[cg * 4 + 1] = s1; Pb[cg * 4 + 2] = s2; Pb[cg * 4 + 3] = s3;
    Pb[256 + cg * 4 + 0] = q0; Pb[256 + cg * 4 + 1] = q1;
    Pb[256 + cg * 4 + 2] = q2; Pb[256 + cg * 4 + 3] = q3;
  }
}

// ---------------- batchnorm stats: stage 2 (one block per column) ------------
__global__ __launch_bounds__(256) void bnfinal2_kernel(const float* __restrict__ P, int nblk,
                                                       const float* __restrict__ g,
                                                       const float* __restrict__ b, int ncols,
                                                       float* __restrict__ na,
                                                       float* __restrict__ nb) {
  int c = blockIdx.x;
  int t = threadIdx.x;
  float s = 0.f, q = 0.f;
  for (int i = t; i < nblk; i += 256) {
    s += P[i * 512 + c];
    q += P[i * 512 + 256 + c];
  }
#pragma unroll
  for (int off = 32; off > 0; off >>= 1) {
    s += __shfl_down(s, off, 64);
    q += __shfl_down(q, off, 64);
  }
  __shared__ float ws[4], wq[4];
  if ((t & 63) == 0) { ws[t >> 6] = s; wq[t >> 6] = q; }
  __syncthreads();
  if (t == 0) {
    s = ws[0] + ws[1] + ws[2] + ws[3];
    q = wq[0] + wq[1] + wq[2] + wq[3];
    if (c < ncols) {
      float mean = s / (float)NN;
      float var = q / (float)NN - mean * mean;
      float a = g[c] * rsqrtf(var + 1e-5f);
      na[c] = a;
      nb[c] = b[c] - mean * a;
    } else {
      na[c] = 0.f;  // pad cols -> BN-applied value 0
      nb[c] = 0.f;
    }
  }
}

// ---------------- BN apply: pair -> pre-normalized bf16 hi plane only --------
template <int LD>
__global__ __launch_bounds__(256) void bnapply_kernel(const unsigned* __restrict__ Xp,
                                                      const float* __restrict__ na,
                                                      const float* __restrict__ nb,
                                                      short* __restrict__ Xh) {
  int idx = blockIdx.x * 256 + threadIdx.x;  // over NP * LD/4
  if (idx >= NP * (LD / 4)) return;
  int row = idx / (LD / 4);
  int cg = (idx - row * (LD / 4)) * 4;
  short4b h;
  if (row < NN) {
    uint4 v = *(const uint4*)(Xp + (size_t)row * LD + cg);
    unsigned arr[4] = {v.x, v.y, v.z, v.w};
#pragma unroll
    for (int e = 0; e < 4; e++) {
      float f = bfp2f(arr[e]) * na[cg + e] + nb[cg + e];
      h[e] = (short)f2bf(f);
    }
  } else {
    h = (short4b){0, 0, 0, 0};
  }
  *(short4b*)(Xh + (size_t)row * LD + cg) = h;
}

// ---------------- fused MLP kernel ----------------
// 128-node tile, 512 threads = 8 waves in 2(M) x 4(N); acc[4][4] per wave.
// Activations in LDS as a single bf16 hi plane (55 KB, 2 blocks/CU = 16
// waves/CU). Weights = global hi/lo planes (L2-hot), plain loads (R12:
// explicit register prefetch is compiler-defeated). 2-term split precision:
// acc += ah*bh + ah*bl. NaN guard: epi zeroes LDS cols [208,216) of every
// row + 16-short tail (R10 lesson: NaN*0=NaN in MFMA).
template <bool READOUT>
__global__ __launch_bounds__(512, 4) void fused_kernel(
    const short* __restrict__ Agh, int glda,
    const short* __restrict__ W1h, const short* __restrict__ W1l,
    const short* __restrict__ W2h, const short* __restrict__ W2l,
    const short* __restrict__ W3h, const short* __restrict__ W3l,
    const short* __restrict__ W4h, const short* __restrict__ W4l,
    const float* __restrict__ b1, const float* __restrict__ b2,
    const float* __restrict__ b3, const float* __restrict__ b4,
    unsigned* __restrict__ xp, short* __restrict__ xq, int t,
    const float* __restrict__ w4ro, const int* __restrict__ mol,
    float* __restrict__ out) {
  __shared__ short ldsH[128 * SP + 16];
  const int tid = threadIdx.x;
  const int wave = tid >> 6, lane = tid & 63, ln = lane & 15, quad = lane >> 4;
  const int wm = wave >> 2;   // M half: rows wm*64 .. wm*64+63
  const int wn = wave & 3;    // N quarter
  const int bm = blockIdx.x * 128;
  const int ntile = (wn == 0) ? 4 : 3;
  const int n0col = (wn == 0) ? 0 : 16 + wn * 48;  // 0, 64, 112, 160

  if (tid < 16) ldsH[128 * SP + tid] = 0;  // zero tail for row-127 k-overread

  f32x4 acc[4][4];

  auto layer = [&](auto ga_tag, const short* __restrict__ Wh,
                   const short* __restrict__ Wl, int Kpad, int KP) {
    constexpr bool GA = decltype(ga_tag)::value;
#pragma unroll
    for (int i = 0; i < 4; i++)
#pragma unroll
      for (int j = 0; j < 4; j++) acc[i][j] = (f32x4){0.f, 0.f, 0.f, 0.f};
    for (int k0 = 0; k0 < KP; k0 += 32) {
      short8b ah[4], bh[4], bl[4];
#pragma unroll
      for (int i = 0; i < 4; i++) {
        int r = wm * 64 + i * 16 + ln;
        if constexpr (GA)
          ah[i] = *(const short8b*)(Agh + (size_t)(bm + r) * glda + k0 + quad * 8);
        else
          ah[i] = *(const short8b*)(ldsH + r * SP + k0 + quad * 8);
      }
#pragma unroll
      for (int j = 0; j < 4; j++)
        if (j < ntile) {
          const size_t o = (size_t)(n0col + j * 16 + ln) * Kpad + k0 + quad * 8;
          bh[j] = *(const short8b*)(Wh + o);
          bl[j] = *(const short8b*)(Wl + o);
        }
#pragma unroll
      for (int j = 0; j < 4; j++)
        if (j < ntile)
#pragma unroll
          for (int i = 0; i < 4; i++) {
            acc[i][j] = __builtin_amdgcn_mfma_f32_16x16x32_bf16(ah[i], bh[j], acc[i][j], 0, 0, 0);
            acc[i][j] = __builtin_amdgcn_mfma_f32_16x16x32_bf16(ah[i], bl[j], acc[i][j], 0, 0, 0);
          }
    }
  };

  // epilogue: relu(acc+bias) -> hi plane; zero cols [208,216) of every row
  auto epi = [&](const float* __restrict__ bias) {
    __syncthreads();
#pragma unroll
    for (int i = 0; i < 4; i++)
#pragma unroll
      for (int j = 0; j < 4; j++)
        if (j < ntile)
#pragma unroll
          for (int r = 0; r < 4; r++) {
            int row = wm * 64 + i * 16 + quad * 4 + r;
            int col = n0col + j * 16 + ln;
            float v = acc[i][j][r] + (col < HH ? bias[col] : 0.f);
            v = fmaxf(v, 0.f);
            ldsH[row * SP + col] = (short)f2bf(v);
          }
    {  // NaN guard: cols 208..215 (4 threads/row x 1 dword, 512 thr = 128 rows)
      int row = tid >> 2;
      *(int*)(ldsH + row * SP + 208 + (tid & 3) * 2) = 0;
    }
    __syncthreads();
  };

  if (!READOUT) {
    layer(std::true_type{}, W1h, W1l, 96, 96);
    epi(b1);
    layer(std::false_type{}, W2h, W2l, 224, 224);
    epi(b2);
    layer(std::false_type{}, W3h, W3l, 224, 224);
    epi(b3);
    // ---- L4 (200->64): wave (wm,wn) -> rows wm*64.., cols wn*16..+15 ----
    f32x4 a4[4];
#pragma unroll
    for (int i = 0; i < 4; i++) a4[i] = (f32x4){0.f, 0.f, 0.f, 0.f};
    for (int k0 = 0; k0 < 224; k0 += 32) {
      short8b ah[4], bh, bl;
#pragma unroll
      for (int i = 0; i < 4; i++) {
        int r = wm * 64 + i * 16 + ln;
        ah[i] = *(const short8b*)(ldsH + r * SP + k0 + quad * 8);
      }
      const size_t o = (size_t)(wn * 16 + ln) * 224 + k0 + quad * 8;
      bh = *(const short8b*)(W4h + o);
      bl = *(const short8b*)(W4l + o);
#pragma unroll
      for (int i = 0; i < 4; i++) {
        a4[i] = __builtin_amdgcn_mfma_f32_16x16x32_bf16(ah[i], bh, a4[i], 0, 0, 0);
        a4[i] = __builtin_amdgcn_mfma_f32_16x16x32_bf16(ah[i], bl, a4[i], 0, 0, 0);
      }
    }
    // x-update: x[t+1] = x[t] + 0.1*(h3@W4 + b4); also maintain hi-plane xq
#pragma unroll
    for (int i = 0; i < 4; i++)
#pragma unroll
      for (int r = 0; r < 4; r++) {
        int grow = bm + wm * 64 + i * 16 + quad * 4 + r;
        int col = wn * 16 + ln;
        if (grow < NN) {
          float v = a4[i][r] + b4[col];
          size_t base = (size_t)grow * RD;
          float old = bfp2f(xp[base + (size_t)t * ED + col]);
          unsigned pk = packsplit(old + 0.1f * v);
          xp[base + (size_t)(t + 1) * ED + col] = pk;
          xq[base + (size_t)(t + 1) * ED + col] = (short)(pk & 0xffffu);
        }
      }
  } else {
    layer(std::true_type{}, W1h, W1l, 256, 256);
    epi(b1);
    layer(std::false_type{}, W2h, W2l, 224, 224);
    epi(b2);
    layer(std::false_type{}, W3h, W3l, 224, 224);
    epi(b3);
    // fused final layer (200->1) + molecule segment-sum: 4 threads per row
    int row = tid >> 2;
    int grow = bm + row;
    float s = 0.f;
    for (int c = (tid & 3); c < HH; c += 4)
      s += ubf2f((unsigned short)ldsH[row * SP + c]) * w4ro[c];
    s += __shfl_xor(s, 1, 64);
    s += __shfl_xor(s, 2, 64);
    if ((tid & 3) == 0 && grow < NN) atomicAdd(&out[mol[grow]], s + b4[0]);
  }
}

// ---------------- host launcher ----------------
extern "C" void kernel_launch(void* const* d_in, const int* in_sizes, int n_in,
                              void* d_out, int out_size, void* d_ws, size_t ws_size,
                              hipStream_t stream) {
  const int* z_i = (const int*)d_in[0];
  const int* e_src = (const int*)d_in[1];
  const int* e_snk = ((const int*)d_in[1]) + EE;
  const float* dist = (const float*)d_in[2];
  const int* mol = (const int*)d_in[3];
  const float* emb = (const float*)d_in[4];
  const float* up_bn_g = (const float*)d_in[5];
  const float* up_bn_b = (const float*)d_in[6];
  const float* up_w1 = (const float*)d_in[7];
  const float* up_b1 = (const float*)d_in[8];
  const float* up_w2 = (const float*)d_in[9];
  const float* up_b2 = (const float*)d_in[10];
  const float* up_w3 = (const float*)d_in[11];
  const float* up_b3 = (const float*)d_in[12];
  const float* up_w4 = (const float*)d_in[13];
  const float* up_b4 = (const float*)d_in[14];
  const float* ro_bn_g = (const float*)d_in[15];
  const float* ro_bn_b = (const float*)d_in[16];
  const float* ro_w1 = (const float*)d_in[17];
  const float* ro_b1 = (const float*)d_in[18];
  const float* ro_w2 = (const float*)d_in[19];
  const float* ro_b2 = (const float*)d_in[20];
  const float* ro_w3 = (const float*)d_in[21];
  const float* ro_b3 = (const float*)d_in[22];
  const float* ro_w4 = (const float*)d_in[23];
  const float* ro_b4 = (const float*)d_in[24];
  float* out = (float*)d_out;

  char* p = (char*)d_ws;
  auto alloc = [&](size_t bytes) {
    void* r = (void*)p;
    p += (bytes + 255) & ~(size_t)255;
    return r;
  };
  unsigned* x_p = (unsigned*)alloc((size_t)NN * RD * 4);   // fp32-equiv pair
  short* x_q = (short*)alloc((size_t)NN * RD * 2);         // x hi plane (gather reads)
  unsigned* m_p = (unsigned*)alloc((size_t)NN * 96 * 4);
  short* mh = (short*)alloc((size_t)NP * 96 * 2);          // BN-applied m hi plane
  short* xh = (short*)alloc((size_t)NP * RD * 2);          // BN-applied x hi plane
  int* ssink = (int*)alloc((size_t)EE * 4);
  float* sdist = (float*)alloc((size_t)EE * 4);
  int* offs = (int*)alloc((size_t)(NN + 1) * 4);
  int* deg = (int*)alloc((size_t)NN * 4);
  int* cursor = (int*)alloc((size_t)NN * 4);
  int* Psum = (int*)alloc((size_t)SNB * 4);
  int* Poff = (int*)alloc((size_t)SNB * 4);
  float* P = (float*)alloc((size_t)NPB2 * 512 * 4);
  float* na = (float*)alloc(256 * 4);
  float* nb = (float*)alloc(256 * 4);
  // weight planes (transposed, padded)
  short* w1h = (short*)alloc((size_t)TT * 208 * 96 * 2);
  short* w1l = (short*)alloc((size_t)TT * 208 * 96 * 2);
  short* w2h = (short*)alloc((size_t)TT * 208 * 224 * 2);
  short* w2l = (short*)alloc((size_t)TT * 208 * 224 * 2);
  short* w3h = (short*)alloc((size_t)TT * 208 * 224 * 2);
  short* w3l = (short*)alloc((size_t)TT * 208 * 224 * 2);
  short* w4h = (short*)alloc((size_t)TT * 64 * 224 * 2);
  short* w4l = (short*)alloc((size_t)TT * 64 * 224 * 2);
  short* r1h = (short*)alloc((size_t)208 * 256 * 2);
  short* r1l = (short*)alloc((size_t)208 * 256 * 2);
  short* r2h = (short*)alloc((size_t)208 * 224 * 2);
  short* r2l = (short*)alloc((size_t)208 * 224 * 2);
  short* r3h = (short*)alloc((size_t)208 * 224 * 2);
  short* r3l = (short*)alloc((size_t)208 * 224 * 2);

  hipMemsetAsync(deg, 0, (size_t)NN * 4, stream);
  hipMemsetAsync(out, 0, (size_t)NMOL * 4, stream);

  WDs descs;
  descs.d[0] = {up_w1, w1h, w1l, MD, HH, 96, 208, TT};
  descs.d[1] = {up_w2, w2h, w2l, HH, HH, 224, 208, TT};
  descs.d[2] = {up_w3, w3h, w3l, HH, HH, 224, 208, TT};
  descs.d[3] = {up_w4, w4h, w4l, HH, ED, 224, 64, TT};
  descs.d[4] = {ro_w1, r1h, r1l, RD, HH, 256, 208, 1};
  descs.d[5] = {ro_w2, r2h, r2l, HH, HH, 224, 208, 1};
  descs.d[6] = {ro_w3, r3h, r3l, HH, HH, 224, 208, 1};
  wprep_kernel<<<dim3(546, 7), 256, 0, stream>>>(descs);

  emb_kernel<<<(NN * ED + 255) / 256, 256, 0, stream>>>(z_i, emb, x_p, x_q);
  hist_kernel<<<(EE + 255) / 256, 256, 0, stream>>>(e_src, deg);
  scanA_kernel<<<SNB, 256, 0, stream>>>(deg, Psum);
  scanB_kernel<<<1, 256, 0, stream>>>(Psum, Poff);
  scanC_kernel<<<SNB, 256, 0, stream>>>(deg, Poff, offs, cursor);
  scatter_kernel<<<(EE + 255) / 256, 256, 0, stream>>>(e_src, e_snk, dist, cursor, ssink, sdist);

  const int gM = NP / 128;  // 391

  for (int t = 0; t < TT; t++) {
    gather_kernel<<<(NN + 3) / 4, 256, 0, stream>>>(offs, ssink, sdist, x_q, t * ED, m_p);
    colstats2_kernel<96><<<NPB2, 256, 0, stream>>>(m_p, P);
    bnfinal2_kernel<<<256, 256, 0, stream>>>(P, NPB2, up_bn_g + t * MD, up_bn_b + t * MD, MD,
                                             na, nb);
    bnapply_kernel<96><<<(NP * 24 + 255) / 256, 256, 0, stream>>>(m_p, na, nb, mh);
    fused_kernel<false><<<gM, 512, 0, stream>>>(
        mh, 96,
        w1h + (size_t)t * 208 * 96, w1l + (size_t)t * 208 * 96,
        w2h + (size_t)t * 208 * 224, w2l + (size_t)t * 208 * 224,
        w3h + (size_t)t * 208 * 224, w3l + (size_t)t * 208 * 224,
        w4h + (size_t)t * 64 * 224, w4l + (size_t)t * 64 * 224,
        up_b1 + t * HH, up_b2 + t * HH, up_b3 + t * HH, up_b4 + t * ED,
        x_p, x_q, t, nullptr, nullptr, nullptr);
  }

  colstats2_kernel<256><<<NPB2, 256, 0, stream>>>(x_p, P);
  bnfinal2_kernel<<<256, 256, 0, stream>>>(P, NPB2, ro_bn_g, ro_bn_b, RD, na, nb);
  bnapply_kernel<256><<<(NP * 64 + 255) / 256, 256, 0, stream>>>(x_p, na, nb, xh);
  fused_kernel<true><<<gM, 512, 0, stream>>>(
      xh, 256,
      r1h, r1l, r2h, r2l, r3h, r3l, nullptr, nullptr,
      ro_b1, ro_b2, ro_b3, ro_b4,
      nullptr, nullptr, 0, ro_w4, mol, out);

  (void)in_sizes; (void)n_in; (void)out_size; (void)ws_size;
}

// Round 15
// 701.006 us; speedup vs baseline: 1.3900x; 1.0914x over previous
//
#include <hip/hip_runtime.h>
#include <hip/hip_bf16.h>
#include <type_traits>

#define NN 50000
#define NP 50048   // NN padded to 64*782
#define EE 800000
#define TT 3
#define ED 64
#define NS 23
#define MD 87
#define HH 200
#define NMOL 2048
#define RD 256

#define SP 216     // LDS hi-plane stride (shorts)
#define NPB2 512   // colstats partial blocks
#define SNB ((NN + 255) / 256)  // 196 scan blocks

typedef __attribute__((ext_vector_type(8))) short short8b;
typedef __attribute__((ext_vector_type(4))) short short4b;
typedef __attribute__((ext_vector_type(4))) float f32x4;

// ---- bf16 helpers ----
__device__ __forceinline__ unsigned short f2bf(float f) {
  unsigned u = __float_as_uint(f);
  return (unsigned short)((u + 0x7fffu + ((u >> 16) & 1u)) >> 16);
}
__device__ __forceinline__ float ubf2f(unsigned short h) {
  return __uint_as_float(((unsigned)h) << 16);
}
// interleaved pair in one u32: low16 = hi-bf16, high16 = lo-bf16 (fp32-equivalent)
__device__ __forceinline__ float bfp2f(unsigned p) {
  return __uint_as_float(p << 16) + __uint_as_float(p & 0xffff0000u);
}
__device__ __forceinline__ unsigned packsplit(float v) {
  unsigned short h = f2bf(v);
  unsigned short l = f2bf(v - ubf2f(h));
  return (unsigned)h | ((unsigned)l << 16);
}

// ---------------- weight prep: fp32 [T][K][N] -> bf16 hi/lo planes [T][Npad][Kpad] ----
struct WD { const float* src; short* dh; short* dl; int K, N, Kpad, Npad, T; };
struct WDs { WD d[7]; };

__global__ __launch_bounds__(256) void wprep_kernel(WDs W) {
  WD w = W.d[blockIdx.y];
  int per = w.Npad * w.Kpad;
  int total = w.T * per;
  for (int idx = blockIdx.x * 256 + threadIdx.x; idx < total; idx += gridDim.x * 256) {
    int t = idx / per;
    int r = idx - t * per;
    int n = r / w.Kpad;
    int k = r - n * w.Kpad;
    float v = 0.f;
    if (k < w.K && n < w.N) v = w.src[((size_t)t * w.K + k) * w.N + n];
    unsigned short h = f2bf(v);
    unsigned short l = f2bf(v - ubf2f(h));
    w.dh[idx] = (short)h;
    w.dl[idx] = (short)l;
  }
}

// ---------------- embedding -> x slice 0 (pair + hi plane) ----------------
__global__ __launch_bounds__(256) void emb_kernel(const int* __restrict__ z,
                                                  const float* __restrict__ emb,
                                                  unsigned* __restrict__ xp,
                                                  short* __restrict__ xq) {
  int idx = blockIdx.x * 256 + threadIdx.x;
  if (idx >= NN * ED) return;
  int i = idx >> 6, d = idx & 63;
  unsigned pk = packsplit(emb[z[i] * ED + d]);
  xp[(size_t)i * RD + d] = pk;
  xq[(size_t)i * RD + d] = (short)(pk & 0xffffu);
}

// ---------------- CSR build ----------------
__global__ __launch_bounds__(256) void hist_kernel(const int* __restrict__ src,
                                                   int* __restrict__ deg) {
  int e = blockIdx.x * 256 + threadIdx.x;
  if (e < EE) atomicAdd(&deg[src[e]], 1);
}

// 3-stage parallel exclusive scan of deg[0..NN)
__global__ __launch_bounds__(256) void scanA_kernel(const int* __restrict__ deg,
                                                    int* __restrict__ Psum) {
  int i = blockIdx.x * 256 + threadIdx.x;
  int v = (i < NN) ? deg[i] : 0;
#pragma unroll
  for (int off = 32; off > 0; off >>= 1) v += __shfl_down(v, off, 64);
  __shared__ int ws[4];
  if ((threadIdx.x & 63) == 0) ws[threadIdx.x >> 6] = v;
  __syncthreads();
  if (threadIdx.x == 0) Psum[blockIdx.x] = ws[0] + ws[1] + ws[2] + ws[3];
}

__global__ __launch_bounds__(256) void scanB_kernel(const int* __restrict__ Psum,
                                                    int* __restrict__ Poff) {
  __shared__ int sh[256];
  int t = threadIdx.x;
  int v = (t < SNB) ? Psum[t] : 0;
  sh[t] = v;
  __syncthreads();
  for (int off = 1; off < 256; off <<= 1) {
    int u = (t >= off) ? sh[t - off] : 0;
    __syncthreads();
    sh[t] += u;
    __syncthreads();
  }
  if (t < SNB) Poff[t] = sh[t] - v;  // exclusive
}

__global__ __launch_bounds__(256) void scanC_kernel(const int* __restrict__ deg,
                                                    const int* __restrict__ Poff,
                                                    int* __restrict__ offs,
                                                    int* __restrict__ cursor) {
  __shared__ int sh[256];
  int t = threadIdx.x;
  int i = blockIdx.x * 256 + t;
  int v = (i < NN) ? deg[i] : 0;
  sh[t] = v;
  __syncthreads();
  for (int off = 1; off < 256; off <<= 1) {
    int u = (t >= off) ? sh[t - off] : 0;
    __syncthreads();
    sh[t] += u;
    __syncthreads();
  }
  int excl = Poff[blockIdx.x] + sh[t] - v;
  if (i < NN) {
    offs[i] = excl;
    cursor[i] = excl;
    if (i == NN - 1) offs[NN] = excl + v;
  }
}

__global__ __launch_bounds__(256) void scatter_kernel(const int* __restrict__ src,
                                                      const int* __restrict__ snk,
                                                      const float* __restrict__ dist,
                                                      int* __restrict__ cursor,
                                                      int* __restrict__ ssink,
                                                      float* __restrict__ sdist) {
  int e = blockIdx.x * 256 + threadIdx.x;
  if (e >= EE) return;
  int p = atomicAdd(&cursor[src[e]], 1);
  ssink[p] = snk[e];
  sdist[p] = dist[e];
}

// ---------------- message gather: one wave per node, hi-plane reads ----------
__global__ __launch_bounds__(256) void gather_kernel(const int* __restrict__ offs,
                                                     const int* __restrict__ ssink,
                                                     const float* __restrict__ sdist,
                                                     const short* __restrict__ xq,
                                                     int toff, unsigned* __restrict__ m) {
  int node = blockIdx.x * 4 + (threadIdx.x >> 6);
  int lane = threadIdx.x & 63;
  if (node >= NN) return;
  float shift = (float)(0.8 + 0.1 * (double)lane);
  int e0 = offs[node], e1 = offs[node + 1];
  float ax0 = 0.f, ax1 = 0.f, ar0 = 0.f, ar1 = 0.f;
  int j = e0;
  for (; j + 4 <= e1; j += 4) {
    int s0 = ssink[j], s1 = ssink[j + 1], s2 = ssink[j + 2], s3 = ssink[j + 3];
    float d0 = sdist[j], d1 = sdist[j + 1], d2 = sdist[j + 2], d3 = sdist[j + 3];
    float x0 = ubf2f((unsigned short)xq[(size_t)s0 * RD + toff + lane]);
    float x1 = ubf2f((unsigned short)xq[(size_t)s1 * RD + toff + lane]);
    float x2 = ubf2f((unsigned short)xq[(size_t)s2 * RD + toff + lane]);
    float x3 = ubf2f((unsigned short)xq[(size_t)s3 * RD + toff + lane]);
    ax0 += x0 + x2;
    ax1 += x1 + x3;
    if (lane < NS) {
      float u0 = d0 - shift, u1 = d1 - shift, u2 = d2 - shift, u3 = d3 - shift;
      ar0 += __expf(-u0 * u0) + __expf(-u2 * u2);
      ar1 += __expf(-u1 * u1) + __expf(-u3 * u3);
    }
  }
  for (; j < e1; j++) {
    int s = ssink[j];
    float d = sdist[j];
    ax0 += ubf2f((unsigned short)xq[(size_t)s * RD + toff + lane]);
    if (lane < NS) {
      float u = d - shift;
      ar0 += __expf(-u * u);
    }
  }
  float accx = ax0 + ax1, accr = ar0 + ar1;
  if (lane < NS) m[node * 96 + lane] = packsplit(accr);
  m[node * 96 + NS + lane] = packsplit(accx);
}

// ---------------- batchnorm stats: stage 1 (vectorized, 512 blocks) ----------
template <int LD>
__global__ __launch_bounds__(256) void colstats2_kernel(const unsigned* __restrict__ X,
                                                        float* __restrict__ P) {
  constexpr int CG = LD / 4;
  constexpr int RPB = 256 / CG;
  const int t = threadIdx.x;
  const int cg = t % CG, rin = t / CG;
  float s0 = 0, s1 = 0, s2 = 0, s3 = 0, q0 = 0, q1 = 0, q2 = 0, q3 = 0;
  if (rin < RPB) {
    for (int r = blockIdx.x * RPB + rin; r < NN; r += gridDim.x * RPB) {
      uint4 v = *(const uint4*)(X + (size_t)r * LD + cg * 4);
      float f0 = bfp2f(v.x), f1 = bfp2f(v.y), f2 = bfp2f(v.z), f3 = bfp2f(v.w);
      s0 += f0; q0 += f0 * f0;
      s1 += f1; q1 += f1 * f1;
      s2 += f2; q2 += f2 * f2;
      s3 += f3; q3 += f3 * f3;
    }
  }
  __shared__ float sh[256][8];
  sh[t][0] = s0; sh[t][1] = s1; sh[t][2] = s2; sh[t][3] = s3;
  sh[t][4] = q0; sh[t][5] = q1; sh[t][6] = q2; sh[t][7] = q3;
  __syncthreads();
  if (rin == 0) {
#pragma unroll
    for (int rr = 1; rr < RPB; rr++) {
      const float* o = sh[rr * CG + cg];
      s0 += o[0]; s1 += o[1]; s2 += o[2]; s3 += o[3];
      q0 += o[4]; q1 += o[5]; q2 += o[6]; q3 += o[7];
    }
    float* Pb = P + blockIdx.x * 512;
    Pb[cg * 4 + 0] = s0; Pb[cg * 4 + 1] = s1; Pb[cg * 4 + 2] = s2; Pb[cg * 4 + 3] = s3;
    Pb[256 + cg * 4 + 0] = q0; Pb[256 + cg * 4 + 1] = q1;
    Pb[256 + cg * 4 + 2] = q2; Pb[256 + cg * 4 + 3] = q3;
  }
}

// ---------------- batchnorm stats: stage 2 (one block per column) ------------
__global__ __launch_bounds__(256) void bnfinal2_kernel(const float* __restrict__ P, int nblk,
                                                       const float* __restrict__ g,
                                                       const float* __restrict__ b, int ncols,
                                                       float* __restrict__ na,
                                                       float* __restrict__ nb) {
  int c = blockIdx.x;
  int t = threadIdx.x;
  float s = 0.f, q = 0.f;
  for (int i = t; i < nblk; i += 256) {
    s += P[i * 512 + c];
    q += P[i * 512 + 256 + c];
  }
#pragma unroll
  for (int off = 32; off > 0; off >>= 1) {
    s += __shfl_down(s, off, 64);
    q += __shfl_down(q, off, 64);
  }
  __shared__ float ws[4], wq[4];
  if ((t & 63) == 0) { ws[t >> 6] = s; wq[t >> 6] = q; }
  __syncthreads();
  if (t == 0) {
    s = ws[0] + ws[1] + ws[2] + ws[3];
    q = wq[0] + wq[1] + wq[2] + wq[3];
    if (c < ncols) {
      float mean = s / (float)NN;
      float var = q / (float)NN - mean * mean;
      float a = g[c] * rsqrtf(var + 1e-5f);
      na[c] = a;
      nb[c] = b[c] - mean * a;
    } else {
      na[c] = 0.f;  // pad cols -> BN-applied value 0
      nb[c] = 0.f;
    }
  }
}

// ---------------- BN apply: pair -> pre-normalized bf16 hi plane only --------
template <int LD>
__global__ __launch_bounds__(256) void bnapply_kernel(const unsigned* __restrict__ Xp,
                                                      const float* __restrict__ na,
                                                      const float* __restrict__ nb,
                                                      short* __restrict__ Xh) {
  int idx = blockIdx.x * 256 + threadIdx.x;  // over NP * LD/4
  if (idx >= NP * (LD / 4)) return;
  int row = idx / (LD / 4);
  int cg = (idx - row * (LD / 4)) * 4;
  short4b h;
  if (row < NN) {
    uint4 v = *(const uint4*)(Xp + (size_t)row * LD + cg);
    unsigned arr[4] = {v.x, v.y, v.z, v.w};
#pragma unroll
    for (int e = 0; e < 4; e++) {
      float f = bfp2f(arr[e]) * na[cg + e] + nb[cg + e];
      h[e] = (short)f2bf(f);
    }
  } else {
    h = (short4b){0, 0, 0, 0};
  }
  *(short4b*)(Xh + (size_t)row * LD + cg) = h;
}

// ---------------- fused MLP kernel ----------------
// R15: 64-node tile, 512 threads = 8 waves ALL N-split (13 n-tiles of 16 over
// 208 cols: waves 0-4 take 2, waves 5-7 take 1), acc[4][2]. LDS halves to
// 27.7 KB -> 5-block LDS capacity; grid doubles to 782 -> ~3 blocks/CU
// resident, ~24 waves/CU, and phase-offset blocks break the barrier lockstep
// that capped R14 at 9 waves/CU / MfmaUtil 10%. Weights = global hi/lo
// planes (L2-hot), plain loads. 2-term split precision: acc += ah*bh + ah*bl.
// NaN guard: epi zeroes LDS cols [208,216) of every row + 16-short tail
// (R10 lesson: NaN*0=NaN in MFMA).
template <bool READOUT>
__global__ __launch_bounds__(512, 4) void fused_kernel(
    const short* __restrict__ Agh, int glda,
    const short* __restrict__ W1h, const short* __restrict__ W1l,
    const short* __restrict__ W2h, const short* __restrict__ W2l,
    const short* __restrict__ W3h, const short* __restrict__ W3l,
    const short* __restrict__ W4h, const short* __restrict__ W4l,
    const float* __restrict__ b1, const float* __restrict__ b2,
    const float* __restrict__ b3, const float* __restrict__ b4,
    unsigned* __restrict__ xp, short* __restrict__ xq, int t,
    const float* __restrict__ w4ro, const int* __restrict__ mol,
    float* __restrict__ out) {
  __shared__ short ldsH[64 * SP + 16];
  const int tid = threadIdx.x;
  const int wave = tid >> 6, lane = tid & 63, ln = lane & 15, quad = lane >> 4;
  const int bm = blockIdx.x * 64;
  const int ntile = (wave < 5) ? 2 : 1;
  const int n0col = ((wave < 5) ? 2 * wave : wave + 5) * 16;  // 13 tiles of 16

  if (tid < 16) ldsH[64 * SP + tid] = 0;  // zero tail for row-63 k-overread

  f32x4 acc[4][2];

  auto layer = [&](auto ga_tag, const short* __restrict__ Wh,
                   const short* __restrict__ Wl, int Kpad, int KP) {
    constexpr bool GA = decltype(ga_tag)::value;
#pragma unroll
    for (int i = 0; i < 4; i++)
#pragma unroll
      for (int j = 0; j < 2; j++) acc[i][j] = (f32x4){0.f, 0.f, 0.f, 0.f};
    for (int k0 = 0; k0 < KP; k0 += 32) {
      short8b ah[4], bh[2], bl[2];
#pragma unroll
      for (int i = 0; i < 4; i++) {
        int r = i * 16 + ln;
        if constexpr (GA)
          ah[i] = *(const short8b*)(Agh + (size_t)(bm + r) * glda + k0 + quad * 8);
        else
          ah[i] = *(const short8b*)(ldsH + r * SP + k0 + quad * 8);
      }
#pragma unroll
      for (int j = 0; j < 2; j++)
        if (j < ntile) {
          const size_t o = (size_t)(n0col + j * 16 + ln) * Kpad + k0 + quad * 8;
          bh[j] = *(const short8b*)(Wh + o);
          bl[j] = *(const short8b*)(Wl + o);
        }
#pragma unroll
      for (int j = 0; j < 2; j++)
        if (j < ntile)
#pragma unroll
          for (int i = 0; i < 4; i++) {
            acc[i][j] = __builtin_amdgcn_mfma_f32_16x16x32_bf16(ah[i], bh[j], acc[i][j], 0, 0, 0);
            acc[i][j] = __builtin_amdgcn_mfma_f32_16x16x32_bf16(ah[i], bl[j], acc[i][j], 0, 0, 0);
          }
    }
  };

  // epilogue: relu(acc+bias) -> hi plane; zero cols [208,216) of every row
  auto epi = [&](const float* __restrict__ bias) {
    __syncthreads();
#pragma unroll
    for (int i = 0; i < 4; i++)
#pragma unroll
      for (int j = 0; j < 2; j++)
        if (j < ntile)
#pragma unroll
          for (int r = 0; r < 4; r++) {
            int row = i * 16 + quad * 4 + r;
            int col = n0col + j * 16 + ln;
            float v = acc[i][j][r] + (col < HH ? bias[col] : 0.f);
            v = fmaxf(v, 0.f);
            ldsH[row * SP + col] = (short)f2bf(v);
          }
    // NaN guard: cols 208..215 (8 threads/row x 1 short, 512 thr = 64 rows)
    ldsH[(tid >> 3) * SP + 208 + (tid & 7)] = 0;
    __syncthreads();
  };

  if (!READOUT) {
    layer(std::true_type{}, W1h, W1l, 96, 96);
    epi(b1);
    layer(std::false_type{}, W2h, W2l, 224, 224);
    epi(b2);
    layer(std::false_type{}, W3h, W3l, 224, 224);
    epi(b3);
    // ---- L4 (200->64): 2M x 4N wave split so all 8 waves work ----
    const int wm4 = wave & 1, wn4 = wave >> 1;  // rows wm4*32.., cols wn4*16..
    f32x4 a4[2];
#pragma unroll
    for (int i = 0; i < 2; i++) a4[i] = (f32x4){0.f, 0.f, 0.f, 0.f};
    for (int k0 = 0; k0 < 224; k0 += 32) {
      short8b ah[2], bh, bl;
#pragma unroll
      for (int i = 0; i < 2; i++) {
        int r = wm4 * 32 + i * 16 + ln;
        ah[i] = *(const short8b*)(ldsH + r * SP + k0 + quad * 8);
      }
      const size_t o = (size_t)(wn4 * 16 + ln) * 224 + k0 + quad * 8;
      bh = *(const short8b*)(W4h + o);
      bl = *(const short8b*)(W4l + o);
#pragma unroll
      for (int i = 0; i < 2; i++) {
        a4[i] = __builtin_amdgcn_mfma_f32_16x16x32_bf16(ah[i], bh, a4[i], 0, 0, 0);
        a4[i] = __builtin_amdgcn_mfma_f32_16x16x32_bf16(ah[i], bl, a4[i], 0, 0, 0);
      }
    }
    // x-update: x[t+1] = x[t] + 0.1*(h3@W4 + b4); also maintain hi-plane xq
#pragma unroll
    for (int i = 0; i < 2; i++)
#pragma unroll
      for (int r = 0; r < 4; r++) {
        int grow = bm + wm4 * 32 + i * 16 + quad * 4 + r;
        int col = wn4 * 16 + ln;
        if (grow < NN) {
          float v = a4[i][r] + b4[col];
          size_t base = (size_t)grow * RD;
          float old = bfp2f(xp[base + (size_t)t * ED + col]);
          unsigned pk = packsplit(old + 0.1f * v);
          xp[base + (size_t)(t + 1) * ED + col] = pk;
          xq[base + (size_t)(t + 1) * ED + col] = (short)(pk & 0xffffu);
        }
      }
  } else {
    layer(std::true_type{}, W1h, W1l, 256, 256);
    epi(b1);
    layer(std::false_type{}, W2h, W2l, 224, 224);
    epi(b2);
    layer(std::false_type{}, W3h, W3l, 224, 224);
    epi(b3);
    // fused final layer (200->1) + molecule segment-sum: 8 threads per row
    int row = tid >> 3;
    int grow = bm + row;
    float s = 0.f;
    for (int c = (tid & 7); c < HH; c += 8)
      s += ubf2f((unsigned short)ldsH[row * SP + c]) * w4ro[c];
    s += __shfl_xor(s, 1, 64);
    s += __shfl_xor(s, 2, 64);
    s += __shfl_xor(s, 4, 64);
    if ((tid & 7) == 0 && grow < NN) atomicAdd(&out[mol[grow]], s + b4[0]);
  }
}

// ---------------- host launcher ----------------
extern "C" void kernel_launch(void* const* d_in, const int* in_sizes, int n_in,
                              void* d_out, int out_size, void* d_ws, size_t ws_size,
                              hipStream_t stream) {
  const int* z_i = (const int*)d_in[0];
  const int* e_src = (const int*)d_in[1];
  const int* e_snk = ((const int*)d_in[1]) + EE;
  const float* dist = (const float*)d_in[2];
  const int* mol = (const int*)d_in[3];
  const float* emb = (const float*)d_in[4];
  const float* up_bn_g = (const float*)d_in[5];
  const float* up_bn_b = (const float*)d_in[6];
  const float* up_w1 = (const float*)d_in[7];
  const float* up_b1 = (const float*)d_in[8];
  const float* up_w2 = (const float*)d_in[9];
  const float* up_b2 = (const float*)d_in[10];
  const float* up_w3 = (const float*)d_in[11];
  const float* up_b3 = (const float*)d_in[12];
  const float* up_w4 = (const float*)d_in[13];
  const float* up_b4 = (const float*)d_in[14];
  const float* ro_bn_g = (const float*)d_in[15];
  const float* ro_bn_b = (const float*)d_in[16];
  const float* ro_w1 = (const float*)d_in[17];
  const float* ro_b1 = (const float*)d_in[18];
  const float* ro_w2 = (const float*)d_in[19];
  const float* ro_b2 = (const float*)d_in[20];
  const float* ro_w3 = (const float*)d_in[21];
  const float* ro_b3 = (const float*)d_in[22];
  const float* ro_w4 = (const float*)d_in[23];
  const float* ro_b4 = (const float*)d_in[24];
  float* out = (float*)d_out;

  char* p = (char*)d_ws;
  auto alloc = [&](size_t bytes) {
    void* r = (void*)p;
    p += (bytes + 255) & ~(size_t)255;
    return r;
  };
  unsigned* x_p = (unsigned*)alloc((size_t)NN * RD * 4);   // fp32-equiv pair
  short* x_q = (short*)alloc((size_t)NN * RD * 2);         // x hi plane (gather reads)
  unsigned* m_p = (unsigned*)alloc((size_t)NN * 96 * 4);
  short* mh = (short*)alloc((size_t)NP * 96 * 2);          // BN-applied m hi plane
  short* xh = (short*)alloc((size_t)NP * RD * 2);          // BN-applied x hi plane
  int* ssink = (int*)alloc((size_t)EE * 4);
  float* sdist = (float*)alloc((size_t)EE * 4);
  int* offs = (int*)alloc((size_t)(NN + 1) * 4);
  int* deg = (int*)alloc((size_t)NN * 4);
  int* cursor = (int*)alloc((size_t)NN * 4);
  int* Psum = (int*)alloc((size_t)SNB * 4);
  int* Poff = (int*)alloc((size_t)SNB * 4);
  float* P = (float*)alloc((size_t)NPB2 * 512 * 4);
  float* na = (float*)alloc(256 * 4);
  float* nb = (float*)alloc(256 * 4);
  // weight planes (transposed, padded)
  short* w1h = (short*)alloc((size_t)TT * 208 * 96 * 2);
  short* w1l = (short*)alloc((size_t)TT * 208 * 96 * 2);
  short* w2h = (short*)alloc((size_t)TT * 208 * 224 * 2);
  short* w2l = (short*)alloc((size_t)TT * 208 * 224 * 2);
  short* w3h = (short*)alloc((size_t)TT * 208 * 224 * 2);
  short* w3l = (short*)alloc((size_t)TT * 208 * 224 * 2);
  short* w4h = (short*)alloc((size_t)TT * 64 * 224 * 2);
  short* w4l = (short*)alloc((size_t)TT * 64 * 224 * 2);
  short* r1h = (short*)alloc((size_t)208 * 256 * 2);
  short* r1l = (short*)alloc((size_t)208 * 256 * 2);
  short* r2h = (short*)alloc((size_t)208 * 224 * 2);
  short* r2l = (short*)alloc((size_t)208 * 224 * 2);
  short* r3h = (short*)alloc((size_t)208 * 224 * 2);
  short* r3l = (short*)alloc((size_t)208 * 224 * 2);

  hipMemsetAsync(deg, 0, (size_t)NN * 4, stream);
  hipMemsetAsync(out, 0, (size_t)NMOL * 4, stream);

  WDs descs;
  descs.d[0] = {up_w1, w1h, w1l, MD, HH, 96, 208, TT};
  descs.d[1] = {up_w2, w2h, w2l, HH, HH, 224, 208, TT};
  descs.d[2] = {up_w3, w3h, w3l, HH, HH, 224, 208, TT};
  descs.d[3] = {up_w4, w4h, w4l, HH, ED, 224, 64, TT};
  descs.d[4] = {ro_w1, r1h, r1l, RD, HH, 256, 208, 1};
  descs.d[5] = {ro_w2, r2h, r2l, HH, HH, 224, 208, 1};
  descs.d[6] = {ro_w3, r3h, r3l, HH, HH, 224, 208, 1};
  wprep_kernel<<<dim3(546, 7), 256, 0, stream>>>(descs);

  emb_kernel<<<(NN * ED + 255) / 256, 256, 0, stream>>>(z_i, emb, x_p, x_q);
  hist_kernel<<<(EE + 255) / 256, 256, 0, stream>>>(e_src, deg);
  scanA_kernel<<<SNB, 256, 0, stream>>>(deg, Psum);
  scanB_kernel<<<1, 256, 0, stream>>>(Psum, Poff);
  scanC_kernel<<<SNB, 256, 0, stream>>>(deg, Poff, offs, cursor);
  scatter_kernel<<<(EE + 255) / 256, 256, 0, stream>>>(e_src, e_snk, dist, cursor, ssink, sdist);

  const int gM = NP / 64;  // 782

  for (int t = 0; t < TT; t++) {
    gather_kernel<<<(NN + 3) / 4, 256, 0, stream>>>(offs, ssink, sdist, x_q, t * ED, m_p);
    colstats2_kernel<96><<<NPB2, 256, 0, stream>>>(m_p, P);
    bnfinal2_kernel<<<256, 256, 0, stream>>>(P, NPB2, up_bn_g + t * MD, up_bn_b + t * MD, MD,
                                             na, nb);
    bnapply_kernel<96><<<(NP * 24 + 255) / 256, 256, 0, stream>>>(m_p, na, nb, mh);
    fused_kernel<false><<<gM, 512, 0, stream>>>(
        mh, 96,
        w1h + (size_t)t * 208 * 96, w1l + (size_t)t * 208 * 96,
        w2h + (size_t)t * 208 * 224, w2l + (size_t)t * 208 * 224,
        w3h + (size_t)t * 208 * 224, w3l + (size_t)t * 208 * 224,
        w4h + (size_t)t * 64 * 224, w4l + (size_t)t * 64 * 224,
        up_b1 + t * HH, up_b2 + t * HH, up_b3 + t * HH, up_b4 + t * ED,
        x_p, x_q, t, nullptr, nullptr, nullptr);
  }

  colstats2_kernel<256><<<NPB2, 256, 0, stream>>>(x_p, P);
  bnfinal2_kernel<<<256, 256, 0, stream>>>(P, NPB2, ro_bn_g, ro_bn_b, RD, na, nb);
  bnapply_kernel<256><<<(NP * 64 + 255) / 256, 256, 0, stream>>>(x_p, na, nb, xh);
  fused_kernel<true><<<gM, 512, 0, stream>>>(
      xh, 256,
      r1h, r1l, r2h, r2l, r3h, r3l, nullptr, nullptr,
      ro_b1, ro_b2, ro_b3, ro_b4,
      nullptr, nullptr, 0, ro_w4, mol, out);

  (void)in_sizes; (void)n_in; (void)out_size; (void)ws_size;
}